// Round 3
// baseline (3822.589 us; speedup 1.0000x reference)
//
#include <hip/hip_runtime.h>
#include <stdint.h>

typedef unsigned long long u64;
typedef unsigned int u32;
typedef unsigned char u8;

#define Bn 4
#define Nv 8192
#define Fd 64
#define Ed 65536
#define Kv 4096
#define TGTK 4096   // N - K kills allowed
#define NW 256      // alive bitmap words per batch (8192 bits)
#define SC 8192     // bitonic LDS chunk
#define SELCAP 16384
#define SELM 15360  // selection rank target (needs ~12.5k; capacity margin ~1k)

// ---------------- workspace layout (bytes) ----------------
#define WS_FLAGS   ((size_t)0)                          // u32 adj-format presence bits
#define WS_ACCCNT  ((size_t)256)                        // Bn u32
#define WS_FB      ((size_t)512)                        // u32 fallback flag
#define WS_SELN    ((size_t)768)                        // Bn u32 select slot counters
#define WS_CUT     ((size_t)1024)                       // Bn*2 u32: cutBin, S
#define WS_HIST    ((size_t)4096)                       // Bn*4096 u32 = 64 KB
#define WS_OUTBITS ((size_t)131072)                     // Bn*Kv*128 u32 = 8 MB
#define WS_ZERO_BYTES (WS_OUTBITS + (size_t)Bn*Kv*128*4)
#define WS_KEYS    (WS_ZERO_BYTES)                      // Bn*Ed u64 (8-aligned)
#define WS_PACK    (WS_KEYS + (size_t)Bn*Ed*8)          // Bn*Ed u32
#define WS_SPACK   (WS_PACK + (size_t)Bn*Ed*4)          // Bn*Ed u32 (fallback sorted packs)
#define WS_SELK    (WS_SPACK + (size_t)Bn*Ed*4)         // Bn*SELCAP u64
#define WS_SPSEL   (WS_SELK + (size_t)Bn*SELCAP*8)      // Bn*SELCAP u32
#define WS_SQ      (WS_SPSEL + (size_t)Bn*SELCAP*4)     // Bn*Nv f32
#define WS_BND     (WS_SQ + (size_t)Bn*Nv*4)            // Bn*Nv u8
#define WS_MAP     (WS_BND + (size_t)Bn*Nv)             // Bn*Nv i32
#define WS_POS     (WS_MAP + (size_t)Bn*Nv*4)           // Bn*Nv i32
#define WS_PM      (WS_POS + (size_t)Bn*Nv*4)           // Bn*Nv i32
#define WS_ALIVEW  (WS_PM + (size_t)Bn*Nv*4)            // Bn*NW u32
#define WS_ALIST   (WS_ALIVEW + (size_t)Bn*NW*4)        // Bn*Kv i32
#define WS_ACC     (WS_ALIST + (size_t)Bn*Kv*4)         // Bn*TGTK*2 i32

// ---------------- per-vertex: numpy-pairwise sqnorm, boundary, map init + adj format detect ----------------
__global__ void k_vertex(const u8* adj, u32* flags, const float* image, const float* vs,
                         float* sq, u8* bnd, int* map) {
#pragma clang fp contract(off)
    int idx = blockIdx.x * 256 + threadIdx.x; // b*Nv + v, exactly 32768 threads
    const float* row = image + (size_t)idx * Fd;
    float r[8];
#pragma unroll
    for (int j = 0; j < 8; ++j) r[j] = row[j] * row[j];
#pragma unroll
    for (int i = 8; i < 64; i += 8)
#pragma unroll
        for (int j = 0; j < 8; ++j) r[j] += row[i + j] * row[i + j];
    float s = ((r[0] + r[1]) + (r[2] + r[3])) + ((r[4] + r[5]) + (r[6] + r[7]));
    sq[idx] = s;
    float x = vs[(size_t)idx * 2], y = vs[(size_t)idx * 2 + 1];
    const float LO = 0.05f;
    const float HI = (float)(1.0 - 0.05);
    bnd[idx] = ((x < LO) || (x > HI) || (y < LO) || (y > HI)) ? 1 : 0;
    map[idx] = idx & (Nv - 1);
    // adj format detection: sample first 2 MB for nonzero bytes at each offset%4
    const u32* w = (const u32*)adj;
    bool f0 = false, f1 = false, f2 = false, f3 = false;
    for (int i = idx; i < (1 << 19); i += 32768) {
        u32 v = w[i];
        f0 |= (v & 0x000000FFu) != 0;
        f1 |= (v & 0x0000FF00u) != 0;
        f2 |= (v & 0x00FF0000u) != 0;
        f3 |= (v & 0xFF000000u) != 0;
    }
    u32 m = 0;
    if (__ballot(f0)) m |= 1;
    if (__ballot(f1)) m |= 2;
    if (__ballot(f2)) m |= 4;
    if (__ballot(f3)) m |= 8;
    if ((threadIdx.x & 63) == 0 && m) atomicOr(flags, m);
}

// ---------------- per-edge: sort key + packed (v0,v1,ok) ----------------
__global__ void k_edge(const int* edges, const float* sq, const u8* bnd, u64* keys, u32* pack) {
    int idx = blockIdx.x * 256 + threadIdx.x; // b*Ed + e
    if (idx >= Bn * Ed) return;
    int b = idx >> 16, e = idx & (Ed - 1);
    int v0 = edges[(size_t)b * 2 * Ed + e];
    int v1 = edges[(size_t)b * 2 * Ed + Ed + e];
    float c = sq[b * Nv + v0] + sq[b * Nv + v1];
    keys[idx] = ((u64)__float_as_uint(c) << 16) | (u32)e; // cost>=0: bits monotone; id tie-break
    u32 okk = (!bnd[b * Nv + v0] && !bnd[b * Nv + v1]) ? 1u : 0u;
    pack[idx] = (u32)v0 | ((u32)v1 << 13) | (okk << 26);
}

// ---------------- selection: histogram / cutoff / compact ----------------
__device__ __forceinline__ int cost_bin(u64 key) {
    u32 cb = (u32)(key >> 16);
    int bin = (int)(cb >> 13) - 0x21000; // covers cost in [32,512); chi2(128) mass is inside
    return bin < 0 ? 0 : (bin > 4095 ? 4095 : bin);
}

__global__ void k_hist(const u64* keys, u32* hist) {
    int idx = blockIdx.x * 256 + threadIdx.x;
    if (idx >= Bn * Ed) return;
    int b = idx >> 16;
    atomicAdd(&hist[b * 4096 + cost_bin(keys[idx])], 1u);
}

__global__ __launch_bounds__(1024) void k_cut(const u32* hist, u32* cutS, u32* fb) {
    int b = blockIdx.x;
    const u32* h = hist + b * 4096;
    __shared__ u32 part[1024];
    __shared__ u32 poff[1024];
    __shared__ u32 cutbin;
    int tid = threadIdx.x;
    u32 h4[4];
    u32 s = 0;
#pragma unroll
    for (int q = 0; q < 4; ++q) { h4[q] = h[tid * 4 + q]; s += h4[q]; }
    part[tid] = s;
    if (tid == 0) cutbin = 4095;
    __syncthreads();
    if (tid == 0) {
        u32 run = 0;
        for (int i = 0; i < 1024; ++i) { poff[i] = run; run += part[i]; }
    }
    __syncthreads();
    u32 run = poff[tid];
#pragma unroll
    for (int q = 0; q < 4; ++q) {
        run += h4[q];
        if (run >= SELM) { atomicMin(&cutbin, (u32)(tid * 4 + q)); break; }
    }
    __syncthreads();
    if (tid == (int)(cutbin >> 2)) {
        u32 r2 = poff[tid];
        for (int q = 0; q <= (int)(cutbin & 3); ++q) r2 += h4[q];
        cutS[b * 2] = cutbin;
        cutS[b * 2 + 1] = r2;
        if (r2 > SELCAP) atomicOr(fb, 1u); // capacity exceeded -> full fallback
    }
}

__global__ void k_select(const u64* keys, const u32* cutS, u32* selN, u64* selK) {
    int idx = blockIdx.x * 256 + threadIdx.x;
    if (idx >= Bn * Ed) return;
    int b = idx >> 16;
    u64 key = keys[idx];
    if ((u32)cost_bin(key) <= cutS[b * 2]) {
        u32 slot = atomicAdd(&selN[b], 1u);
        if (slot < SELCAP) selK[(size_t)b * SELCAP + slot] = key;
    }
}

// ---------------- bitonic primitives ----------------
__device__ __forceinline__ void bitonic_cas(u64* s, int i, int pa, bool asc) {
    u64 a = s[i], c = s[pa];
    if ((a > c) == asc) { s[i] = c; s[pa] = a; }
}
__device__ __forceinline__ void cex(u64& a, u64& b, bool asc) {
    if ((a > b) == asc) { u64 t = a; a = b; b = t; }
}

// local sort of one 8192-chunk of the selected array (pad >= S with ~0)
__global__ __launch_bounds__(1024) void k_sortL(u64* selK, const u32* cutS) {
    __shared__ u64 s[SC];
    int b = blockIdx.x >> 1, ch = blockIdx.x & 1;
    u64* base = selK + (size_t)b * SELCAP + (size_t)ch * SC;
    int gb = ch * SC;
    int S = (int)cutS[b * 2 + 1] - gb; // valid elems remaining in this chunk
    int t8 = threadIdx.x * 8;
    u64 r[8];
#pragma unroll
    for (int u = 0; u < 8; ++u) r[u] = (t8 + u < S) ? base[t8 + u] : ~0ull;
    // k=2
    cex(r[0], r[1], true); cex(r[2], r[3], false); cex(r[4], r[5], true); cex(r[6], r[7], false);
    // k=4
    cex(r[0], r[2], true); cex(r[1], r[3], true); cex(r[4], r[6], false); cex(r[5], r[7], false);
    cex(r[0], r[1], true); cex(r[2], r[3], true); cex(r[4], r[5], false); cex(r[6], r[7], false);
    // k=8
    {
        bool a8 = (((gb + t8) & 8) == 0);
        cex(r[0], r[4], a8); cex(r[1], r[5], a8); cex(r[2], r[6], a8); cex(r[3], r[7], a8);
        cex(r[0], r[2], a8); cex(r[1], r[3], a8); cex(r[4], r[6], a8); cex(r[5], r[7], a8);
        cex(r[0], r[1], a8); cex(r[2], r[3], a8); cex(r[4], r[5], a8); cex(r[6], r[7], a8);
    }
#pragma unroll
    for (int u = 0; u < 8; ++u) s[t8 + u] = r[u];
    __syncthreads();
    for (int k = 16; k <= SC; k <<= 1) {
        for (int j = k >> 1; j >= 8; j >>= 1) {
#pragma unroll
            for (int p = 0; p < SC / 2048; ++p) {
                int t = p * 1024 + threadIdx.x;
                int i = ((t & ~(j - 1)) << 1) | (t & (j - 1));
                bool asc = (((gb + i) & k) == 0);
                bitonic_cas(s, i, i | j, asc);
            }
            __syncthreads();
        }
        bool asc = (((gb + t8) & k) == 0);
#pragma unroll
        for (int u = 0; u < 8; ++u) r[u] = s[t8 + u];
        cex(r[0], r[4], asc); cex(r[1], r[5], asc); cex(r[2], r[6], asc); cex(r[3], r[7], asc);
        cex(r[0], r[2], asc); cex(r[1], r[3], asc); cex(r[4], r[6], asc); cex(r[5], r[7], asc);
        cex(r[0], r[1], asc); cex(r[2], r[3], asc); cex(r[4], r[5], asc); cex(r[6], r[7], asc);
        if (k == SC) {
#pragma unroll
            for (int u = 0; u < 8; ++u) base[t8 + u] = r[u];
        } else {
#pragma unroll
            for (int u = 0; u < 8; ++u) s[t8 + u] = r[u];
            __syncthreads();
        }
    }
}

// merge stage k=16384 for the 2-chunk selected array: global j=8192 pass + LDS finish per half
__global__ __launch_bounds__(1024) void k_sortM(u64* selK) {
    int b = blockIdx.x;
    u64* base = selK + (size_t)b * SELCAP;
    int tid = threadIdx.x;
#pragma unroll
    for (int p = 0; p < 8; ++p) { // 8192 pairs (i, i+8192), all ascending (k = n)
        int i = p * 1024 + tid;
        u64 a = base[i], c = base[i + SC];
        if (a > c) { base[i] = c; base[i + SC] = a; }
    }
    __syncthreads();
    __shared__ u64 s[SC];
    for (int h = 0; h < 2; ++h) {
        u64* hb = base + h * SC;
#pragma unroll
        for (int p = 0; p < 8; ++p) s[p * 1024 + tid] = hb[p * 1024 + tid];
        __syncthreads();
        for (int j = SC / 2; j >= 8; j >>= 1) {
#pragma unroll
            for (int p = 0; p < SC / 2048; ++p) {
                int t = p * 1024 + tid;
                int i = ((t & ~(j - 1)) << 1) | (t & (j - 1));
                bitonic_cas(s, i, i | j, true);
            }
            __syncthreads();
        }
        int t8 = tid * 8;
        u64 r[8];
#pragma unroll
        for (int u = 0; u < 8; ++u) r[u] = s[t8 + u];
        cex(r[0], r[4], true); cex(r[1], r[5], true); cex(r[2], r[6], true); cex(r[3], r[7], true);
        cex(r[0], r[2], true); cex(r[1], r[3], true); cex(r[4], r[6], true); cex(r[5], r[7], true);
        cex(r[0], r[1], true); cex(r[2], r[3], true); cex(r[4], r[5], true); cex(r[6], r[7], true);
#pragma unroll
        for (int u = 0; u < 8; ++u) hb[t8 + u] = r[u];
        __syncthreads();
    }
}

// permute packs into sorted-selected order
__global__ void k_gatherS(const u64* selK, const u32* pack, u32* spsel) {
    int idx = blockIdx.x * 256 + threadIdx.x; // Bn*SELCAP
    if (idx >= Bn * SELCAP) return;
    int b = idx >> 14;
    u32 id = (u32)(selK[idx] & 0xFFFFu);
    spsel[idx] = pack[(size_t)b * Ed + id];
}

// ---------------- greedy core: 64-edge speculative groups, exact sequential semantics ----------------
__device__ __forceinline__ void greedy_core(const u32* sp, int S, int b, int lane,
        u32* alive, u32* mlane, int* map, u32* aliveW, int* accList, u32* accCnt, u32* fb) {
    for (int i = lane; i < NW; i += 64) alive[i] = 0xFFFFFFFFu;
    for (int i = lane; i < Nv; i += 64) mlane[i] = 64u;
    __syncthreads();
    int nk = 0;
    int G = (S + 63) >> 6;
    u32 pc = sp[lane]; // prefetch group 0 (buffers padded to >= G*64)
    bool done = false;
    for (int g = 0; g < G; ++g) {
        u32 pn = (g + 1 < G) ? sp[(g + 1) * 64 + lane] : 0u;
        bool valid = (g * 64 + lane) < S;
        int v0 = pc & 8191;
        int v1 = (pc >> 13) & 8191;
        bool okk = (pc >> 26) & 1u;
        bool a0 = (alive[v0 >> 5] >> (v0 & 31)) & 1u;
        bool a1 = (alive[v1 >> 5] >> (v1 & 31)) & 1u;
        bool spec = valid && okk && a0 && a1;
        if (spec) atomicMin(&mlane[v1], (u32)lane);
        __syncthreads();
        bool conf = false;
        if (spec) conf = (mlane[v0] < (u32)lane) || (mlane[v1] < (u32)lane);
        u64 specM = __ballot(spec);
        u64 confM = __ballot(conf);
        u64 accM = specM & ~confM;
        u64 rem = confM;
        while (rem) {
            int l = __ffsll((unsigned long long)rem) - 1;
            rem &= rem - 1;
            int bv0 = __shfl(v0, l);
            int bv1 = __shfl(v1, l);
            bool killer = ((accM >> lane) & 1ull) && (lane < l) && (v1 == bv0 || v1 == bv1);
            if (__ballot(killer) == 0ull) accM |= 1ull << l;
        }
        int cnt = __popcll(accM);
        int remK = TGTK - nk;
        bool acc = (accM >> lane) & 1ull;
        if (cnt > remK) { // cap: keep first remK accepts; later edges are past cap anyway
            int rr = __popcll(accM & ((1ull << lane) - 1ull));
            if (acc && rr >= remK) acc = false;
            accM = __ballot(acc);
            cnt = remK;
        }
        if (acc) {
            atomicAnd(&alive[v1 >> 5], ~(1u << (v1 & 31)));
            map[(size_t)b * Nv + v1] = v0;
            int rr = __popcll(accM & ((1ull << lane) - 1ull));
            int slot = nk + rr;
            accList[((size_t)b * TGTK + slot) * 2] = v0;
            accList[((size_t)b * TGTK + slot) * 2 + 1] = v1;
        }
        if (spec) mlane[v1] = 64u;
        nk += cnt;
        __syncthreads();
        if (nk >= TGTK) { done = true; break; }
        pc = pn;
    }
    for (int i = lane; i < NW; i += 64) aliveW[b * NW + i] = alive[i];
    if (lane == 0) {
        accCnt[b] = (u32)nk;
        if (!done && nk < TGTK && fb) atomicOr(fb, 1u); // prefix exhausted -> need full sort
    }
}

__global__ __launch_bounds__(64) void k_greedyP(const u32* spsel, const u32* cutS, int* map,
        u32* aliveW, int* accList, u32* accCnt, u32* fb) {
    __shared__ u32 alive[NW];
    __shared__ u32 mlane[Nv];
    int b = blockIdx.x;
    int S = (int)cutS[b * 2 + 1];
    if (S > SELCAP) S = SELCAP;
    greedy_core(spsel + (size_t)b * SELCAP, S, b, threadIdx.x, alive, mlane,
                map, aliveW, accList, accCnt, fb);
}

// ---------------- fallback: full in-block sort + gather (early-exit unless fb) ----------------
__global__ __launch_bounds__(1024) void k_sortFB(u64* keys, const u32* pack, u32* spackF,
                                                 const u32* fb) {
    if (*fb == 0) return;
    int b = blockIdx.x;
    u64* kb = keys + (size_t)b * Ed;
    __shared__ u64 s[SC];
    int tid = threadIdx.x;
    for (int ch = 0; ch < 8; ++ch) { // local sort of 8 chunks
        u64* cb = kb + ch * SC;
        int gb = ch * SC;
        for (int p = 0; p < 8; ++p) s[p * 1024 + tid] = cb[p * 1024 + tid];
        __syncthreads();
        for (int k = 2; k <= SC; k <<= 1)
            for (int j = k >> 1; j > 0; j >>= 1) {
                for (int p = 0; p < 4; ++p) {
                    int t = p * 1024 + tid;
                    int i = ((t & ~(j - 1)) << 1) | (t & (j - 1));
                    bool asc = (((gb + i) & k) == 0);
                    bitonic_cas(s, i, i | j, asc);
                }
                __syncthreads();
            }
        for (int p = 0; p < 8; ++p) cb[p * 1024 + tid] = s[p * 1024 + tid];
        __syncthreads();
    }
    for (int k = 16384; k <= 65536; k <<= 1) { // merge stages
        for (int j = k >> 1; j >= SC; j >>= 1) {
            for (int p = 0; p < 32; ++p) { // 32768 pairs
                int t = p * 1024 + tid;
                int i = ((t & ~(j - 1)) << 1) | (t & (j - 1));
                bool asc = ((i & k) == 0);
                u64 a = kb[i], c = kb[i | j];
                if ((a > c) == asc) { kb[i] = c; kb[i | j] = a; }
            }
            __syncthreads();
        }
        for (int ch = 0; ch < 8; ++ch) {
            u64* cb = kb + ch * SC;
            bool asc = (((ch * SC) & k) == 0);
            for (int p = 0; p < 8; ++p) s[p * 1024 + tid] = cb[p * 1024 + tid];
            __syncthreads();
            for (int j = SC / 2; j > 0; j >>= 1) {
                for (int p = 0; p < 4; ++p) {
                    int t = p * 1024 + tid;
                    int i = ((t & ~(j - 1)) << 1) | (t & (j - 1));
                    bitonic_cas(s, i, i | j, asc);
                }
                __syncthreads();
            }
            for (int p = 0; p < 8; ++p) cb[p * 1024 + tid] = s[p * 1024 + tid];
            __syncthreads();
        }
    }
    for (int i = tid; i < Ed; i += 1024)
        spackF[(size_t)b * Ed + i] = pack[(size_t)b * Ed + (u32)(kb[i] & 0xFFFFu)];
}

__global__ __launch_bounds__(64) void k_greedyF(const u32* spackF, int* map, u32* aliveW,
        int* accList, u32* accCnt, const u32* fb) {
    if (*fb == 0) return;
    __shared__ u32 alive[NW];
    __shared__ u32 mlane[Nv];
    int b = blockIdx.x;
    for (int i = threadIdx.x; i < Nv; i += 64) map[(size_t)b * Nv + i] = i; // re-init
    greedy_core(spackF + (size_t)b * Ed, Ed, b, threadIdx.x, alive, mlane,
                map, aliveW, accList, accCnt, nullptr);
}

// ---------------- alive ranks: pos[v], alive list, pm[v] = pos[m[v]] ----------------
__global__ __launch_bounds__(256) void k_scan(const u32* aliveW, const int* map,
                                              int* pos, int* pm, int* alist) {
    int b = blockIdx.x, tid = threadIdx.x;
    __shared__ u32 cnt[256];
    __shared__ u32 off[256];
    u32 w = aliveW[b * NW + tid];
    cnt[tid] = __popc(w);
    __syncthreads();
    if (tid == 0) { u32 s = 0; for (int i = 0; i < 256; ++i) { off[i] = s; s += cnt[i]; } }
    __syncthreads();
    u32 base = off[tid];
    int* posb = pos + (size_t)b * Nv;
    int* alb = alist + (size_t)b * Kv;
    for (int bit = 0; bit < 32; ++bit) {
        int v = tid * 32 + bit;
        int p = -1;
        if ((w >> bit) & 1u) {
            if (base < Kv) { p = (int)base; alb[base] = v; }
            base++;
        }
        posb[v] = p;
    }
    __syncthreads();
    const int* mapb = map + (size_t)b * Nv;
    int* pmb = pm + (size_t)b * Nv;
    for (int v = tid; v < Nv; v += 256) pmb[v] = posb[mapb[v]];
}

// ---------------- features: copy surviving rows, then scatter-add absorbed rows ----------------
__global__ void k_fcopy(const float* image, const int* alist, float* outF) {
    int idx = blockIdx.x * 256 + threadIdx.x; // Bn*Kv*16
    if (idx >= Bn * Kv * 16) return;
    int b = idx >> 16, r = idx & 65535;
    int x = r >> 4, f4 = r & 15;
    int src = alist[b * Kv + x];
    const float4* s = (const float4*)(image + ((size_t)(b * Nv + src)) * Fd) + f4;
    float4* d = (float4*)(outF + ((size_t)(b * Kv + x)) * Fd) + f4;
    *d = *s;
}

__global__ __launch_bounds__(64) void k_fscat(const float* image, const int* accList,
                                              const u32* accCnt, const int* pos, float* outF) {
    int b = blockIdx.x >> 12, e = blockIdx.x & 4095;
    if (e >= (int)accCnt[b]) return;
    int v0 = accList[((size_t)b * TGTK + e) * 2];
    int v1 = accList[((size_t)b * TGTK + e) * 2 + 1];
    int x = pos[(size_t)b * Nv + v0];
    if (x < 0) return;
    int f = threadIdx.x;
    atomicAdd(outF + ((size_t)(b * Kv + x)) * Fd + f,
              image[((size_t)(b * Nv + v1)) * Fd + f]);
}

// ---------------- adjacency: merge rows/cols into K-bit bitsets ----------------
__global__ __launch_bounds__(256) void k_merge(const u8* adj, const u32* flags,
                                               const int* pm, u32* outbits) {
    int bi = blockIdx.x; // Bn*Nv
    int b = bi >> 13, i = bi & (Nv - 1);
    int t = pm[(size_t)b * Nv + i];
    if (t < 0) return;
    __shared__ u32 bits[Kv / 32]; // 128 words
    int tid = threadIdx.x;
    if (tid < 128) bits[tid] = 0;
    __syncthreads();
    const int* pmb = pm + (size_t)b * Nv;
    u32 fw = flags[0];
    bool bytefmt = (fw & 1) && (fw & 8);
    auto put = [&](int col) {
        int c = pmb[col];
        if (c >= 0) atomicOr(&bits[c >> 5], 1u << (c & 31));
    };
    if (bytefmt) {
        const uint4* row = (const uint4*)(adj + ((size_t)b * Nv + i) * Nv);
#pragma unroll
        for (int it = 0; it < 2; ++it) {
            uint4 v = row[it * 256 + tid];
            if (v.x | v.y | v.z | v.w) {
                int cb = (it * 256 + tid) * 16;
                u32 wv[4] = { v.x, v.y, v.z, v.w };
                for (int q = 0; q < 4; ++q) {
                    u32 u = wv[q];
                    if (!u) continue;
#pragma unroll
                    for (int kk = 0; kk < 4; ++kk)
                        if ((u >> (8 * kk)) & 0xFFu) put(cb + q * 4 + kk);
                }
            }
        }
    } else {
        const uint4* row = (const uint4*)((const u32*)adj + ((size_t)b * Nv + i) * Nv);
        for (int it = 0; it < 8; ++it) {
            uint4 v = row[it * 256 + tid];
            int cb = (it * 256 + tid) * 4;
            if (v.x) put(cb);
            if (v.y) put(cb + 1);
            if (v.z) put(cb + 2);
            if (v.w) put(cb + 3);
        }
    }
    __syncthreads();
    if (tid < 128) {
        u32 bw = bits[tid];
        if (bw) atomicOr(&outbits[((size_t)b * Kv + t) * 128 + tid], bw);
    }
}

// ---------------- expand bitsets to float adjacency, zero diagonal ----------------
__global__ void k_expand(const u32* outbits, float* out) {
    int idx = blockIdx.x; // Bn*Kv*4
    int tid = threadIdx.x;
    int b = idx >> 14, r = idx & 16383;
    int x = r >> 2, seg = r & 3;
    int c0 = seg * 1024 + tid * 4;
    u32 w = outbits[((size_t)b * Kv + x) * 128 + (c0 >> 5)];
    u32 nib = (w >> (c0 & 31)) & 0xFu;
    float4 f;
    f.x = (nib & 1) ? 1.f : 0.f;
    f.y = (nib & 2) ? 1.f : 0.f;
    f.z = (nib & 4) ? 1.f : 0.f;
    f.w = (nib & 8) ? 1.f : 0.f;
    if (x >= c0 && x < c0 + 4) ((float*)&f)[x - c0] = 0.f;
    *((float4*)(out + ((size_t)(b * Kv + x)) * Kv + c0)) = f;
}

extern "C" void kernel_launch(void* const* d_in, const int* in_sizes, int n_in,
                              void* d_out, int out_size, void* d_ws, size_t ws_size,
                              hipStream_t stream) {
    const u8* adj = (const u8*)d_in[0];
    const float* image = (const float*)d_in[1];
    const float* vs = (const float*)d_in[2];
    const int* edges = (const int*)d_in[3];
    char* ws = (char*)d_ws;
    u32* flags = (u32*)(ws + WS_FLAGS);
    u32* accCnt = (u32*)(ws + WS_ACCCNT);
    u32* fb = (u32*)(ws + WS_FB);
    u32* selN = (u32*)(ws + WS_SELN);
    u32* cutS = (u32*)(ws + WS_CUT);
    u32* hist = (u32*)(ws + WS_HIST);
    u32* outbits = (u32*)(ws + WS_OUTBITS);
    u64* keys = (u64*)(ws + WS_KEYS);
    u32* pack = (u32*)(ws + WS_PACK);
    u32* spackF = (u32*)(ws + WS_SPACK);
    u64* selK = (u64*)(ws + WS_SELK);
    u32* spsel = (u32*)(ws + WS_SPSEL);
    float* sq = (float*)(ws + WS_SQ);
    u8* bnd = (u8*)(ws + WS_BND);
    int* map = (int*)(ws + WS_MAP);
    int* pos = (int*)(ws + WS_POS);
    int* pm = (int*)(ws + WS_PM);
    u32* aliveW = (u32*)(ws + WS_ALIVEW);
    int* alist = (int*)(ws + WS_ALIST);
    int* accList = (int*)(ws + WS_ACC);
    float* outA = (float*)d_out;
    float* outF = outA + (size_t)Bn * Kv * Kv;

    hipMemsetAsync(d_ws, 0, WS_ZERO_BYTES, stream);
    k_vertex<<<Bn * Nv / 256, 256, 0, stream>>>(adj, flags, image, vs, sq, bnd, map);
    k_edge<<<Bn * Ed / 256, 256, 0, stream>>>(edges, sq, bnd, keys, pack);
    k_hist<<<Bn * Ed / 256, 256, 0, stream>>>(keys, hist);
    k_cut<<<Bn, 1024, 0, stream>>>(hist, cutS, fb);
    k_select<<<Bn * Ed / 256, 256, 0, stream>>>(keys, cutS, selN, selK);
    k_sortL<<<Bn * 2, 1024, 0, stream>>>(selK, cutS);
    k_sortM<<<Bn, 1024, 0, stream>>>(selK);
    k_gatherS<<<Bn * SELCAP / 256, 256, 0, stream>>>(selK, pack, spsel);
    k_greedyP<<<Bn, 64, 0, stream>>>(spsel, cutS, map, aliveW, accList, accCnt, fb);
    k_sortFB<<<Bn, 1024, 0, stream>>>(keys, pack, spackF, fb);     // early-exit unless fb
    k_greedyF<<<Bn, 64, 0, stream>>>(spackF, map, aliveW, accList, accCnt, fb); // early-exit
    k_scan<<<Bn, 256, 0, stream>>>(aliveW, map, pos, pm, alist);
    k_fcopy<<<Bn * Kv * 16 / 256, 256, 0, stream>>>(image, alist, outF);
    k_fscat<<<Bn * TGTK, 64, 0, stream>>>(image, accList, accCnt, pos, outF);
    k_merge<<<Bn * Nv, 256, 0, stream>>>(adj, flags, pm, outbits);
    k_expand<<<Bn * Kv * 4, 256, 0, stream>>>(outbits, outA);
}

// Round 4
// 2257.442 us; speedup vs baseline: 1.6933x; 1.6933x over previous
//
#include <hip/hip_runtime.h>
#include <stdint.h>

typedef unsigned long long u64;
typedef unsigned int u32;
typedef unsigned char u8;

#define Bn 4
#define Nv 8192
#define Fd 64
#define Ed 65536
#define Kv 4096
#define TGTK 4096   // N - K kills allowed
#define NW 256      // alive bitmap words per batch (8192 bits)
#define RB 2048     // radix bins (11-bit digit)
#define NB 128      // radix blocks per batch
#define CH 512      // elements per radix block

// ---------------- workspace layout (bytes) ----------------
#define WS_FLAGS   ((size_t)0)                          // u32 adj-format presence bits
#define WS_ACCCNT  ((size_t)256)                        // Bn u32
#define WS_OUTBITS ((size_t)4096)                       // Bn*Kv*128 u32 = 8 MB
#define WS_ZERO_BYTES (WS_OUTBITS + (size_t)Bn*Kv*128*4)
#define WS_HIST    (WS_ZERO_BYTES)                      // Bn*RB*NB u32 = 4 MB (overwritten/pass)
#define WS_KA      (WS_HIST + (size_t)Bn*RB*NB*4)       // Bn*Ed u32
#define WS_PA      (WS_KA + (size_t)Bn*Ed*4)            // Bn*Ed u32
#define WS_KB      (WS_PA + (size_t)Bn*Ed*4)            // Bn*Ed u32
#define WS_PB      (WS_KB + (size_t)Bn*Ed*4)            // Bn*Ed u32
#define WS_SQ      (WS_PB + (size_t)Bn*Ed*4)            // Bn*Nv f32
#define WS_BND     (WS_SQ + (size_t)Bn*Nv*4)            // Bn*Nv u8
#define WS_MAP     (WS_BND + (size_t)Bn*Nv)             // Bn*Nv i32
#define WS_POS     (WS_MAP + (size_t)Bn*Nv*4)           // Bn*Nv i32
#define WS_PM      (WS_POS + (size_t)Bn*Nv*4)           // Bn*Nv i32
#define WS_ALIVEW  (WS_PM + (size_t)Bn*Nv*4)            // Bn*NW u32
#define WS_ALIST   (WS_ALIVEW + (size_t)Bn*NW*4)        // Bn*Kv i32
#define WS_ACC     (WS_ALIST + (size_t)Bn*Kv*4)         // Bn*TGTK*2 i32

// ---------------- per-vertex: numpy-pairwise sqnorm, boundary, map init + adj format detect ----------------
__global__ void k_vertex(const u8* adj, u32* flags, const float* image, const float* vs,
                         float* sq, u8* bnd, int* map) {
#pragma clang fp contract(off)
    int idx = blockIdx.x * 256 + threadIdx.x; // b*Nv + v, exactly 32768 threads
    const float* row = image + (size_t)idx * Fd;
    float r[8];
#pragma unroll
    for (int j = 0; j < 8; ++j) r[j] = row[j] * row[j];
#pragma unroll
    for (int i = 8; i < 64; i += 8)
#pragma unroll
        for (int j = 0; j < 8; ++j) r[j] += row[i + j] * row[i + j];
    float s = ((r[0] + r[1]) + (r[2] + r[3])) + ((r[4] + r[5]) + (r[6] + r[7]));
    sq[idx] = s;
    float x = vs[(size_t)idx * 2], y = vs[(size_t)idx * 2 + 1];
    const float LO = 0.05f;
    const float HI = (float)(1.0 - 0.05);
    bnd[idx] = ((x < LO) || (x > HI) || (y < LO) || (y > HI)) ? 1 : 0;
    map[idx] = idx & (Nv - 1);
    // adj format detection: sample first 2 MB for nonzero bytes at each offset%4
    const u32* w = (const u32*)adj;
    bool f0 = false, f1 = false, f2 = false, f3 = false;
    for (int i = idx; i < (1 << 19); i += 32768) {
        u32 v = w[i];
        f0 |= (v & 0x000000FFu) != 0;
        f1 |= (v & 0x0000FF00u) != 0;
        f2 |= (v & 0x00FF0000u) != 0;
        f3 |= (v & 0xFF000000u) != 0;
    }
    u32 m = 0;
    if (__ballot(f0)) m |= 1;
    if (__ballot(f1)) m |= 2;
    if (__ballot(f2)) m |= 4;
    if (__ballot(f3)) m |= 8;
    if ((threadIdx.x & 63) == 0 && m) atomicOr(flags, m);
}

// ---------------- per-edge: 32-bit cost key + packed payload (v0,v1,ok) ----------------
__global__ void k_edge(const int* edges, const float* sq, const u8* bnd, u32* kA, u32* pA) {
    int idx = blockIdx.x * 256 + threadIdx.x; // b*Ed + e
    if (idx >= Bn * Ed) return;
    int b = idx >> 16, e = idx & (Ed - 1);
    int v0 = edges[(size_t)b * 2 * Ed + e];
    int v1 = edges[(size_t)b * 2 * Ed + Ed + e];
    float c = sq[b * Nv + v0] + sq[b * Nv + v1];
    kA[idx] = __float_as_uint(c); // cost >= 0 -> unsigned bit order == float order
    u32 okk = (!bnd[b * Nv + v0] && !bnd[b * Nv + v1]) ? 1u : 0u;
    pA[idx] = (u32)v0 | ((u32)v1 << 13) | (okk << 26);
    // stability of the radix sort supplies the (cost, edge-id) tie-break order
}

// ---------------- stable LSD radix sort: 3 passes x 11 bits ----------------
__global__ __launch_bounds__(64) void k_rhist(const u32* kin, u32* hist, int sh) {
    int blk = blockIdx.x & (NB - 1), b = blockIdx.x >> 7; // grid Bn*NB
    int lane = threadIdx.x;
    __shared__ u32 h[RB];
    for (int i = lane; i < RB; i += 64) h[i] = 0;
    __syncthreads();
    const u32* kb = kin + (size_t)b * Ed + (size_t)blk * CH;
#pragma unroll
    for (int r = 0; r < CH / 64; ++r) {
        u32 g = (kb[r * 64 + lane] >> sh) & (RB - 1);
        atomicAdd(&h[g], 1u);
    }
    __syncthreads();
    u32* hb = hist + (size_t)b * RB * NB;
    for (int i = lane; i < RB; i += 64) hb[(size_t)i * NB + blk] = h[i];
}

__global__ __launch_bounds__(1024) void k_rscan(u32* hist) {
    int b = blockIdx.x, tid = threadIdx.x;
    u32* hb = hist + (size_t)b * RB * NB; // 262144 entries, layout bin*NB+blk
    const int PT = RB * NB / 1024;        // 256 per thread
    u32 s = 0;
    for (int i = 0; i < PT; ++i) s += hb[tid * PT + i];
    __shared__ u32 sc[1024];
    sc[tid] = s;
    __syncthreads();
    for (int off = 1; off < 1024; off <<= 1) { // Hillis-Steele inclusive scan
        u32 t = (tid >= off) ? sc[tid - off] : 0u;
        __syncthreads();
        sc[tid] += t;
        __syncthreads();
    }
    u32 run = sc[tid] - s; // exclusive
    for (int i = 0; i < PT; ++i) {
        u32 v = hb[tid * PT + i];
        hb[tid * PT + i] = run;
        run += v;
    }
}

__global__ __launch_bounds__(64) void k_rscat(const u32* kin, const u32* pin, const u32* hist,
                                              u32* kout, u32* pout, int sh) {
    int blk = blockIdx.x & (NB - 1), b = blockIdx.x >> 7;
    int lane = threadIdx.x;
    __shared__ u32 cnt[RB];
    for (int i = lane; i < RB; i += 64) cnt[i] = 0;
    __syncthreads();
    const size_t base = (size_t)b * Ed + (size_t)blk * CH;
    const u32* kb = kin + base;
    const u32* pb = pin + base;
    u32 key[CH / 64], pay[CH / 64], gg[CH / 64], gbase[CH / 64];
#pragma unroll
    for (int r = 0; r < CH / 64; ++r) { key[r] = kb[r * 64 + lane]; pay[r] = pb[r * 64 + lane]; }
    const u32* hb = hist + (size_t)b * RB * NB;
#pragma unroll
    for (int r = 0; r < CH / 64; ++r) {
        gg[r] = (key[r] >> sh) & (RB - 1);
        gbase[r] = hb[(size_t)gg[r] * NB + blk];
    }
    u32* ko = kout + (size_t)b * Ed;
    u32* po = pout + (size_t)b * Ed;
    // single wave per block: rounds execute in program order, so the LDS
    // read -> leader atomicAdd sequence gives stable in-block ranks.
#pragma unroll
    for (int r = 0; r < CH / 64; ++r) {
        u32 g = gg[r];
        u64 m = ~0ull;
#pragma unroll
        for (int bb = 0; bb < 11; ++bb) {
            u64 bl = __ballot((g >> bb) & 1u);
            m &= ((g >> bb) & 1u) ? bl : ~bl;
        }
        u32 nlow = (u32)__popcll(m & ((1ull << lane) - 1ull));
        u32 c = cnt[g];
        u32 dst = gbase[r] + c + nlow;
        ko[dst] = key[r];
        po[dst] = pay[r];
        if (nlow == 0) atomicAdd(&cnt[g], (u32)__popcll(m));
    }
}

// ---------------- sequential greedy collapse: 1 wave per batch, 64-edge speculative groups ----------------
__global__ __launch_bounds__(64) void k_greedy(const u32* spack, int* map, u32* aliveW,
                                               int* accList, u32* accCnt) {
    int b = blockIdx.x;
    int lane = threadIdx.x;
    __shared__ u32 alive[NW];
    __shared__ u32 mlane[Nv]; // per-vertex: min lane registering vertex as its v1 this group
    for (int i = lane; i < NW; i += 64) alive[i] = 0xFFFFFFFFu;
    for (int i = lane; i < Nv; i += 64) mlane[i] = 64u;
    const u32* sp = spack + (size_t)b * Ed;
    u32 pc = sp[lane]; // prefetch group 0
    __syncthreads();
    int nk = 0;
    const int G = Ed / 64;
    for (int g = 0; g < G; ++g) {
        u32 pn = (g + 1 < G) ? sp[(g + 1) * 64 + lane] : 0u; // coalesced prefetch
        int v0 = pc & 8191;
        int v1 = (pc >> 13) & 8191;
        bool okk = (pc >> 26) & 1u;
        bool a0 = (alive[v0 >> 5] >> (v0 & 31)) & 1u;
        bool a1 = (alive[v1 >> 5] >> (v1 & 31)) & 1u;
        bool spec = okk && a0 && a1; // exact unless an earlier in-group accept kills my endpoint
        if (spec) atomicMin(&mlane[v1], (u32)lane);
        __syncthreads();
        bool conf = false;
        if (spec) conf = (mlane[v0] < (u32)lane) || (mlane[v1] < (u32)lane);
        u64 specM = __ballot(spec);
        u64 confM = __ballot(conf);
        u64 accM = specM & ~confM; // non-conflicted speculative accepts are exact
        u64 rem = confM;           // resolve conflicted lanes in sequential (edge) order
        while (rem) {
            int l = __ffsll((unsigned long long)rem) - 1;
            rem &= rem - 1;
            int bv0 = __shfl(v0, l);
            int bv1 = __shfl(v1, l);
            bool killer = ((accM >> lane) & 1ull) && (lane < l) && (v1 == bv0 || v1 == bv1);
            if (__ballot(killer) == 0ull) accM |= 1ull << l;
        }
        int cnt = __popcll(accM);
        int remK = TGTK - nk;
        bool acc = (accM >> lane) & 1ull;
        if (cnt > remK) { // kill-count cap: keep first remK accepts
            int rr = __popcll(accM & ((1ull << lane) - 1ull));
            if (acc && rr >= remK) acc = false;
            accM = __ballot(acc);
            cnt = remK;
        }
        if (acc) {
            atomicAnd(&alive[v1 >> 5], ~(1u << (v1 & 31)));
            map[(size_t)b * Nv + v1] = v0;
            int rr = __popcll(accM & ((1ull << lane) - 1ull));
            int slot = nk + rr;
            accList[((size_t)b * TGTK + slot) * 2] = v0;
            accList[((size_t)b * TGTK + slot) * 2 + 1] = v1;
        }
        if (spec) mlane[v1] = 64u; // reset registry
        nk += cnt;
        __syncthreads();
        if (nk >= TGTK) break;
        pc = pn;
    }
    for (int i = lane; i < NW; i += 64) aliveW[b * NW + i] = alive[i];
    if (lane == 0) accCnt[b] = (u32)nk;
}

// ---------------- alive ranks: pos[v], alive list, pm[v] = pos[m[v]] ----------------
__global__ __launch_bounds__(256) void k_scan(const u32* aliveW, const int* map,
                                              int* pos, int* pm, int* alist) {
    int b = blockIdx.x, tid = threadIdx.x;
    __shared__ u32 cnt[256];
    __shared__ u32 off[256];
    u32 w = aliveW[b * NW + tid];
    cnt[tid] = __popc(w);
    __syncthreads();
    if (tid == 0) { u32 s = 0; for (int i = 0; i < 256; ++i) { off[i] = s; s += cnt[i]; } }
    __syncthreads();
    u32 base = off[tid];
    int* posb = pos + (size_t)b * Nv;
    int* alb = alist + (size_t)b * Kv;
    for (int bit = 0; bit < 32; ++bit) {
        int v = tid * 32 + bit;
        int p = -1;
        if ((w >> bit) & 1u) {
            if (base < Kv) { p = (int)base; alb[base] = v; }
            base++;
        }
        posb[v] = p;
    }
    __syncthreads();
    const int* mapb = map + (size_t)b * Nv;
    int* pmb = pm + (size_t)b * Nv;
    for (int v = tid; v < Nv; v += 256) pmb[v] = posb[mapb[v]];
}

// ---------------- features: copy surviving rows, then scatter-add absorbed rows ----------------
__global__ void k_fcopy(const float* image, const int* alist, float* outF) {
    int idx = blockIdx.x * 256 + threadIdx.x; // Bn*Kv*16
    if (idx >= Bn * Kv * 16) return;
    int b = idx >> 16, r = idx & 65535;
    int x = r >> 4, f4 = r & 15;
    int src = alist[b * Kv + x];
    const float4* s = (const float4*)(image + ((size_t)(b * Nv + src)) * Fd) + f4;
    float4* d = (float4*)(outF + ((size_t)(b * Kv + x)) * Fd) + f4;
    *d = *s;
}

__global__ __launch_bounds__(64) void k_fscat(const float* image, const int* accList,
                                              const u32* accCnt, const int* pos, float* outF) {
    int b = blockIdx.x >> 12, e = blockIdx.x & 4095;
    if (e >= (int)accCnt[b]) return;
    int v0 = accList[((size_t)b * TGTK + e) * 2];
    int v1 = accList[((size_t)b * TGTK + e) * 2 + 1];
    int x = pos[(size_t)b * Nv + v0];
    if (x < 0) return;
    int f = threadIdx.x;
    atomicAdd(outF + ((size_t)(b * Kv + x)) * Fd + f,
              image[((size_t)(b * Nv + v1)) * Fd + f]);
}

// ---------------- adjacency: merge rows/cols into K-bit bitsets ----------------
__global__ __launch_bounds__(256) void k_merge(const u8* adj, const u32* flags,
                                               const int* pm, u32* outbits) {
    int bi = blockIdx.x; // Bn*Nv
    int b = bi >> 13, i = bi & (Nv - 1);
    int t = pm[(size_t)b * Nv + i];
    if (t < 0) return;
    __shared__ u32 bits[Kv / 32]; // 128 words
    int tid = threadIdx.x;
    if (tid < 128) bits[tid] = 0;
    __syncthreads();
    const int* pmb = pm + (size_t)b * Nv;
    u32 fw = flags[0];
    bool bytefmt = (fw & 1) && (fw & 8);
    auto put = [&](int col) {
        int c = pmb[col];
        if (c >= 0) atomicOr(&bits[c >> 5], 1u << (c & 31));
    };
    if (bytefmt) {
        const uint4* row = (const uint4*)(adj + ((size_t)b * Nv + i) * Nv);
#pragma unroll
        for (int it = 0; it < 2; ++it) {
            uint4 v = row[it * 256 + tid];
            if (v.x | v.y | v.z | v.w) {
                int cb = (it * 256 + tid) * 16;
                u32 wv[4] = { v.x, v.y, v.z, v.w };
                for (int q = 0; q < 4; ++q) {
                    u32 u = wv[q];
                    if (!u) continue;
#pragma unroll
                    for (int kk = 0; kk < 4; ++kk)
                        if ((u >> (8 * kk)) & 0xFFu) put(cb + q * 4 + kk);
                }
            }
        }
    } else {
        const uint4* row = (const uint4*)((const u32*)adj + ((size_t)b * Nv + i) * Nv);
        for (int it = 0; it < 8; ++it) {
            uint4 v = row[it * 256 + tid];
            int cb = (it * 256 + tid) * 4;
            if (v.x) put(cb);
            if (v.y) put(cb + 1);
            if (v.z) put(cb + 2);
            if (v.w) put(cb + 3);
        }
    }
    __syncthreads();
    if (tid < 128) {
        u32 bw = bits[tid];
        if (bw) atomicOr(&outbits[((size_t)b * Kv + t) * 128 + tid], bw);
    }
}

// ---------------- expand bitsets to float adjacency, zero diagonal ----------------
__global__ void k_expand(const u32* outbits, float* out) {
    int idx = blockIdx.x; // Bn*Kv*4
    int tid = threadIdx.x;
    int b = idx >> 14, r = idx & 16383;
    int x = r >> 2, seg = r & 3;
    int c0 = seg * 1024 + tid * 4;
    u32 w = outbits[((size_t)b * Kv + x) * 128 + (c0 >> 5)];
    u32 nib = (w >> (c0 & 31)) & 0xFu;
    float4 f;
    f.x = (nib & 1) ? 1.f : 0.f;
    f.y = (nib & 2) ? 1.f : 0.f;
    f.z = (nib & 4) ? 1.f : 0.f;
    f.w = (nib & 8) ? 1.f : 0.f;
    if (x >= c0 && x < c0 + 4) ((float*)&f)[x - c0] = 0.f;
    *((float4*)(out + ((size_t)(b * Kv + x)) * Kv + c0)) = f;
}

extern "C" void kernel_launch(void* const* d_in, const int* in_sizes, int n_in,
                              void* d_out, int out_size, void* d_ws, size_t ws_size,
                              hipStream_t stream) {
    const u8* adj = (const u8*)d_in[0];
    const float* image = (const float*)d_in[1];
    const float* vs = (const float*)d_in[2];
    const int* edges = (const int*)d_in[3];
    char* ws = (char*)d_ws;
    u32* flags = (u32*)(ws + WS_FLAGS);
    u32* accCnt = (u32*)(ws + WS_ACCCNT);
    u32* outbits = (u32*)(ws + WS_OUTBITS);
    u32* hist = (u32*)(ws + WS_HIST);
    u32* kA = (u32*)(ws + WS_KA);
    u32* pA = (u32*)(ws + WS_PA);
    u32* kB = (u32*)(ws + WS_KB);
    u32* pB = (u32*)(ws + WS_PB);
    float* sq = (float*)(ws + WS_SQ);
    u8* bnd = (u8*)(ws + WS_BND);
    int* map = (int*)(ws + WS_MAP);
    int* pos = (int*)(ws + WS_POS);
    int* pm = (int*)(ws + WS_PM);
    u32* aliveW = (u32*)(ws + WS_ALIVEW);
    int* alist = (int*)(ws + WS_ALIST);
    int* accList = (int*)(ws + WS_ACC);
    float* outA = (float*)d_out;
    float* outF = outA + (size_t)Bn * Kv * Kv;

    hipMemsetAsync(d_ws, 0, WS_ZERO_BYTES, stream);
    k_vertex<<<Bn * Nv / 256, 256, 0, stream>>>(adj, flags, image, vs, sq, bnd, map);
    k_edge<<<Bn * Ed / 256, 256, 0, stream>>>(edges, sq, bnd, kA, pA);
    // stable LSD radix sort by 32-bit cost key, payload = pack (3 x 11-bit passes)
    k_rhist<<<Bn * NB, 64, 0, stream>>>(kA, hist, 0);
    k_rscan<<<Bn, 1024, 0, stream>>>(hist);
    k_rscat<<<Bn * NB, 64, 0, stream>>>(kA, pA, hist, kB, pB, 0);
    k_rhist<<<Bn * NB, 64, 0, stream>>>(kB, hist, 11);
    k_rscan<<<Bn, 1024, 0, stream>>>(hist);
    k_rscat<<<Bn * NB, 64, 0, stream>>>(kB, pB, hist, kA, pA, 11);
    k_rhist<<<Bn * NB, 64, 0, stream>>>(kA, hist, 22);
    k_rscan<<<Bn, 1024, 0, stream>>>(hist);
    k_rscat<<<Bn * NB, 64, 0, stream>>>(kA, pA, hist, kB, pB, 22);
    k_greedy<<<Bn, 64, 0, stream>>>(pB, map, aliveW, accList, accCnt);
    k_scan<<<Bn, 256, 0, stream>>>(aliveW, map, pos, pm, alist);
    k_fcopy<<<Bn * Kv * 16 / 256, 256, 0, stream>>>(image, alist, outF);
    k_fscat<<<Bn * TGTK, 64, 0, stream>>>(image, accList, accCnt, pos, outF);
    k_merge<<<Bn * Nv, 256, 0, stream>>>(adj, flags, pm, outbits);
    k_expand<<<Bn * Kv * 4, 256, 0, stream>>>(outbits, outA);
}

// Round 5
// 2063.880 us; speedup vs baseline: 1.8521x; 1.0938x over previous
//
#include <hip/hip_runtime.h>
#include <stdint.h>

typedef unsigned long long u64;
typedef unsigned int u32;
typedef unsigned char u8;

#define Bn 4
#define Nv 8192
#define Fd 64
#define Ed 65536
#define Kv 4096
#define TGTK 4096   // N - K kills allowed
#define NW 256      // alive bitmap words per batch (8192 bits)
#define QB 4096     // value-quantized bins per batch
#define BCAP 256    // per-bin capacity (peak expected ~60..100)

// ---------------- workspace layout (bytes) ----------------
#define WS_FLAGS   ((size_t)0)                          // u32 adj-format presence bits
#define WS_ACCCNT  ((size_t)256)                        // Bn u32
#define WS_FB      ((size_t)512)                        // u32 fallback flag
#define WS_MM      ((size_t)768)                        // Bn*2 u32: max(~minbits), max(bits)
#define WS_HIST    ((size_t)4096)                       // Bn*QB u32 = 64 KB
#define WS_CTR     (WS_HIST + (size_t)Bn*QB*4)          // Bn*QB u32 = 64 KB
#define WS_OUTBITS (WS_CTR + (size_t)Bn*QB*4)           // Bn*Kv*128 u32 = 8 MB
#define WS_ZERO_BYTES (WS_OUTBITS + (size_t)Bn*Kv*128*4)
#define WS_OFF     (WS_ZERO_BYTES)                      // Bn*4104 u32 (4097 used)
#define WS_KFULL   (WS_OFF + (size_t)Bn*4104*4)         // Bn*Ed u64 (cost<<16|e)
#define WS_PACK    (WS_KFULL + (size_t)Bn*Ed*8)         // Bn*Ed u32
#define WS_BKEY    (WS_PACK + (size_t)Bn*Ed*4)          // Bn*Ed u64 binned keys
#define WS_BPK     (WS_BKEY + (size_t)Bn*Ed*8)          // Bn*Ed u32 binned packs
#define WS_SPACK   (WS_BPK + (size_t)Bn*Ed*4)           // Bn*Ed u32 sorted packs
#define WS_SQ      (WS_SPACK + (size_t)Bn*Ed*4)         // Bn*Nv f32
#define WS_BND     (WS_SQ + (size_t)Bn*Nv*4)            // Bn*Nv u8
#define WS_MAP     (WS_BND + (size_t)Bn*Nv)             // Bn*Nv i32
#define WS_POS     (WS_MAP + (size_t)Bn*Nv*4)           // Bn*Nv i32
#define WS_PM      (WS_POS + (size_t)Bn*Nv*4)           // Bn*Nv i32
#define WS_ALIVEW  (WS_PM + (size_t)Bn*Nv*4)            // Bn*NW u32
#define WS_ALIST   (WS_ALIVEW + (size_t)Bn*NW*4)        // Bn*Kv i32
#define WS_ACC     (WS_ALIST + (size_t)Bn*Kv*4)         // Bn*TGTK*2 i32

// ---------------- per-vertex: numpy-pairwise sqnorm, boundary, map init + adj format detect ----------------
__global__ void k_vertex(const u8* adj, u32* flags, const float* image, const float* vs,
                         float* sq, u8* bnd, int* map) {
#pragma clang fp contract(off)
    int idx = blockIdx.x * 256 + threadIdx.x; // b*Nv + v, exactly 32768 threads
    const float* row = image + (size_t)idx * Fd;
    float r[8];
#pragma unroll
    for (int j = 0; j < 8; ++j) r[j] = row[j] * row[j];
#pragma unroll
    for (int i = 8; i < 64; i += 8)
#pragma unroll
        for (int j = 0; j < 8; ++j) r[j] += row[i + j] * row[i + j];
    float s = ((r[0] + r[1]) + (r[2] + r[3])) + ((r[4] + r[5]) + (r[6] + r[7]));
    sq[idx] = s;
    float x = vs[(size_t)idx * 2], y = vs[(size_t)idx * 2 + 1];
    const float LO = 0.05f;
    const float HI = (float)(1.0 - 0.05);
    bnd[idx] = ((x < LO) || (x > HI) || (y < LO) || (y > HI)) ? 1 : 0;
    map[idx] = idx & (Nv - 1);
    // adj format detection: sample first 2 MB for nonzero bytes at each offset%4
    const u32* w = (const u32*)adj;
    bool f0 = false, f1 = false, f2 = false, f3 = false;
    for (int i = idx; i < (1 << 19); i += 32768) {
        u32 v = w[i];
        f0 |= (v & 0x000000FFu) != 0;
        f1 |= (v & 0x0000FF00u) != 0;
        f2 |= (v & 0x00FF0000u) != 0;
        f3 |= (v & 0xFF000000u) != 0;
    }
    u32 m = 0;
    if (__ballot(f0)) m |= 1;
    if (__ballot(f1)) m |= 2;
    if (__ballot(f2)) m |= 4;
    if (__ballot(f3)) m |= 8;
    if ((threadIdx.x & 63) == 0 && m) atomicOr(flags, m);
}

// ---------------- per-edge: full key (cost<<16|e), pack, per-batch cost min/max ----------------
__global__ void k_edge(const int* edges, const float* sq, const u8* bnd,
                       u64* kfull, u32* pack, u32* mm) {
    int idx = blockIdx.x * 256 + threadIdx.x; // b*Ed + e (blocks never straddle batches)
    if (idx >= Bn * Ed) return;
    int b = idx >> 16, e = idx & (Ed - 1);
    int v0 = edges[(size_t)b * 2 * Ed + e];
    int v1 = edges[(size_t)b * 2 * Ed + Ed + e];
    float c = sq[b * Nv + v0] + sq[b * Nv + v1];
    u32 cb = __float_as_uint(c); // cost >= 0 -> unsigned bit order == float order
    kfull[idx] = ((u64)cb << 16) | (u32)e;
    u32 okk = (!bnd[b * Nv + v0] && !bnd[b * Nv + v1]) ? 1u : 0u;
    pack[idx] = (u32)v0 | ((u32)v1 << 13) | (okk << 26);
    // wave-reduce min/max of cost bits, one atomic pair per wave
    u32 mn = cb, mx = cb;
#pragma unroll
    for (int o = 32; o; o >>= 1) {
        u32 a = (u32)__shfl_xor((int)mn, o);
        u32 d = (u32)__shfl_xor((int)mx, o);
        mn = mn < a ? mn : a;
        mx = mx > d ? mx : d;
    }
    if ((threadIdx.x & 63) == 0) {
        atomicMax(&mm[b * 2], ~mn);     // min via max of complement (zero-init safe)
        atomicMax(&mm[b * 2 + 1], mx);
    }
}

__device__ __forceinline__ int qbin(u32 cb, u32 mm0, u32 mm1) {
    float minC = __uint_as_float(~mm0);
    float maxC = __uint_as_float(mm1);
    float span = maxC - minC;
    float scale = (float)QB / (span > 1e-30f ? span : 1e-30f);
    int bin = (int)((__uint_as_float(cb) - minC) * scale);
    return bin < 0 ? 0 : (bin > QB - 1 ? QB - 1 : bin);
}

// ---------------- bucket histogram (LDS per block -> global) ----------------
__global__ __launch_bounds__(256) void k_qhist(const u64* kfull, const u32* mm, u32* hist) {
    __shared__ u32 lh[QB];
    int tid = threadIdx.x;
    for (int i = tid; i < QB; i += 256) lh[i] = 0;
    __syncthreads();
    size_t base = (size_t)blockIdx.x * 2048; // 128 blocks, batch-aligned
    int b = (int)(base >> 16);
    u32 mm0 = mm[b * 2], mm1 = mm[b * 2 + 1];
#pragma unroll
    for (int r = 0; r < 8; ++r) {
        u32 cb = (u32)(kfull[base + r * 256 + tid] >> 16);
        atomicAdd(&lh[qbin(cb, mm0, mm1)], 1u);
    }
    __syncthreads();
    for (int i = tid; i < QB; i += 256) {
        u32 v = lh[i];
        if (v) atomicAdd(&hist[b * QB + i], v);
    }
}

// ---------------- scan 4096 bins per batch -> off[4097] ----------------
__global__ __launch_bounds__(1024) void k_qscan(const u32* hist, u32* off) {
    int b = blockIdx.x, tid = threadIdx.x;
    const u32* h = hist + b * QB;
    u32 h4[4];
    u32 s = 0;
#pragma unroll
    for (int q = 0; q < 4; ++q) { h4[q] = h[tid * 4 + q]; s += h4[q]; }
    __shared__ u32 sc[1024];
    sc[tid] = s;
    __syncthreads();
    for (int o = 1; o < 1024; o <<= 1) {
        u32 t = (tid >= o) ? sc[tid - o] : 0u;
        __syncthreads();
        sc[tid] += t;
        __syncthreads();
    }
    u32 run = sc[tid] - s; // exclusive
    u32* ob = off + b * 4104;
#pragma unroll
    for (int q = 0; q < 4; ++q) { ob[tid * 4 + q] = run; run += h4[q]; }
    if (tid == 1023) ob[QB] = sc[1023];
}

// ---------------- scatter into bin segments (unstable; total order restored by binsort) ----------------
__global__ void k_qscat(const u64* kfull, const u32* pack, const u32* mm, const u32* off,
                        u32* ctr, u64* bkey, u32* bpk) {
    int idx = blockIdx.x * 256 + threadIdx.x;
    if (idx >= Bn * Ed) return;
    int b = idx >> 16;
    u64 kf = kfull[idx];
    u32 cb = (u32)(kf >> 16);
    u32 e = (u32)(kf & 0xFFFFu);
    int bin = qbin(cb, mm[b * 2], mm[b * 2 + 1]);
    u32 slot = atomicAdd(&ctr[b * QB + bin], 1u);
    u32 dst = off[b * 4104 + bin] + slot; // always within segment (segment len == bin count)
    bkey[(size_t)b * Ed + dst] = ((u64)cb << 24) | ((u64)e << 8) | (u64)(slot & 255u);
    bpk[(size_t)b * Ed + dst] = pack[idx];
}

// ---------------- per-bin sort: one wave per bin, uniform 256-wide bitonic in LDS ----------------
__global__ __launch_bounds__(256) void k_qsort(const u64* bkey, const u32* bpk, const u32* off,
                                               u32* spack, u32* fb) {
    __shared__ u64 sk[4][BCAP];
    int wave = threadIdx.x >> 6, lane = threadIdx.x & 63;
    int b = blockIdx.x >> 10;
    int bin = (blockIdx.x & 1023) * 4 + wave;
    u32 start = off[b * 4104 + bin];
    u32 end = off[b * 4104 + bin + 1];
    int len = (int)(end - start);
    bool okbin = (len > 0 && len <= BCAP);
    const u64* kb = bkey + (size_t)b * Ed + start;
    for (int i = lane; i < BCAP; i += 64)
        sk[wave][i] = (okbin && i < len) ? kb[i] : ~0ull;
    if (len > BCAP && lane == 0) atomicOr(fb, 1u);
    __syncthreads();
    for (int k = 2; k <= BCAP; k <<= 1) {
        for (int j = k >> 1; j > 0; j >>= 1) {
#pragma unroll
            for (int t = lane; t < BCAP / 2; t += 64) {
                int i = ((t & ~(j - 1)) << 1) | (t & (j - 1));
                bool asc = ((i & k) == 0);
                u64 a = sk[wave][i], c = sk[wave][i | j];
                if ((a > c) == asc) { sk[wave][i] = c; sk[wave][i | j] = a; }
            }
            __syncthreads();
        }
    }
    if (okbin) {
        const u32* pb = bpk + (size_t)b * Ed + start;
        u32* so = spack + (size_t)b * Ed + start;
        for (int r = lane; r < len; r += 64) {
            u32 s = (u32)(sk[wave][r] & 255u);
            so[r] = pb[s];
        }
    }
}

// ---------------- fallback: full in-block bitonic sort + gather (early-exit unless fb) ----------------
__global__ __launch_bounds__(1024) void k_sortFB(u64* kfull, const u32* pack, u32* spack,
                                                 const u32* fb) {
    if (*fb == 0) return;
    int b = blockIdx.x;
    u64* kb = kfull + (size_t)b * Ed;
    __shared__ u64 s[8192];
    int tid = threadIdx.x;
    for (int ch = 0; ch < 8; ++ch) { // local sort of 8 chunks
        u64* cb = kb + ch * 8192;
        int gb = ch * 8192;
        for (int p = 0; p < 8; ++p) s[p * 1024 + tid] = cb[p * 1024 + tid];
        __syncthreads();
        for (int k = 2; k <= 8192; k <<= 1)
            for (int j = k >> 1; j > 0; j >>= 1) {
                for (int p = 0; p < 4; ++p) {
                    int t = p * 1024 + tid;
                    int i = ((t & ~(j - 1)) << 1) | (t & (j - 1));
                    bool asc = (((gb + i) & k) == 0);
                    u64 a = s[i], c = s[i | j];
                    if ((a > c) == asc) { s[i] = c; s[i | j] = a; }
                }
                __syncthreads();
            }
        for (int p = 0; p < 8; ++p) cb[p * 1024 + tid] = s[p * 1024 + tid];
        __syncthreads();
    }
    for (int k = 16384; k <= 65536; k <<= 1) { // merge stages
        for (int j = k >> 1; j >= 8192; j >>= 1) {
            for (int p = 0; p < 32; ++p) {
                int t = p * 1024 + tid;
                int i = ((t & ~(j - 1)) << 1) | (t & (j - 1));
                bool asc = ((i & k) == 0);
                u64 a = kb[i], c = kb[i | j];
                if ((a > c) == asc) { kb[i] = c; kb[i | j] = a; }
            }
            __syncthreads();
        }
        for (int ch = 0; ch < 8; ++ch) {
            u64* cb = kb + ch * 8192;
            bool asc = (((ch * 8192) & k) == 0);
            for (int p = 0; p < 8; ++p) s[p * 1024 + tid] = cb[p * 1024 + tid];
            __syncthreads();
            for (int j = 4096; j > 0; j >>= 1) {
                for (int p = 0; p < 4; ++p) {
                    int t = p * 1024 + tid;
                    int i = ((t & ~(j - 1)) << 1) | (t & (j - 1));
                    u64 a = s[i], c = s[i | j];
                    if ((a > c) == asc) { s[i] = c; s[i | j] = a; }
                }
                __syncthreads();
            }
            for (int p = 0; p < 8; ++p) cb[p * 1024 + tid] = s[p * 1024 + tid];
            __syncthreads();
        }
    }
    for (int i = tid; i < Ed; i += 1024)
        spack[(size_t)b * Ed + i] = pack[(size_t)b * Ed + (u32)(kb[i] & 0xFFFFu)];
}

// ---------------- sequential greedy collapse: 1 wave per batch, 64-edge speculative groups ----------------
__global__ __launch_bounds__(64) void k_greedy(const u32* spack, int* map, u32* aliveW,
                                               int* accList, u32* accCnt) {
    int b = blockIdx.x;
    int lane = threadIdx.x;
    __shared__ u32 alive[NW];
    __shared__ u32 mlane[Nv]; // per-vertex: min lane registering vertex as its v1 this group
    for (int i = lane; i < NW; i += 64) alive[i] = 0xFFFFFFFFu;
    for (int i = lane; i < Nv; i += 64) mlane[i] = 64u;
    const u32* sp = spack + (size_t)b * Ed;
    u32 pc = sp[lane]; // prefetch group 0
    __syncthreads();
    int nk = 0;
    const int G = Ed / 64;
    for (int g = 0; g < G; ++g) {
        u32 pn = (g + 1 < G) ? sp[(g + 1) * 64 + lane] : 0u; // coalesced prefetch
        int v0 = pc & 8191;
        int v1 = (pc >> 13) & 8191;
        bool okk = (pc >> 26) & 1u;
        bool a0 = (alive[v0 >> 5] >> (v0 & 31)) & 1u;
        bool a1 = (alive[v1 >> 5] >> (v1 & 31)) & 1u;
        bool spec = okk && a0 && a1; // exact unless an earlier in-group accept kills my endpoint
        if (spec) atomicMin(&mlane[v1], (u32)lane);
        __syncthreads();
        bool conf = false;
        if (spec) conf = (mlane[v0] < (u32)lane) || (mlane[v1] < (u32)lane);
        u64 specM = __ballot(spec);
        u64 confM = __ballot(conf);
        u64 accM = specM & ~confM; // non-conflicted speculative accepts are exact
        u64 rem = confM;           // resolve conflicted lanes in sequential (edge) order
        while (rem) {
            int l = __ffsll((unsigned long long)rem) - 1;
            rem &= rem - 1;
            int bv0 = __shfl(v0, l);
            int bv1 = __shfl(v1, l);
            bool killer = ((accM >> lane) & 1ull) && (lane < l) && (v1 == bv0 || v1 == bv1);
            if (__ballot(killer) == 0ull) accM |= 1ull << l;
        }
        int cnt = __popcll(accM);
        int remK = TGTK - nk;
        bool acc = (accM >> lane) & 1ull;
        if (cnt > remK) { // kill-count cap: keep first remK accepts
            int rr = __popcll(accM & ((1ull << lane) - 1ull));
            if (acc && rr >= remK) acc = false;
            accM = __ballot(acc);
            cnt = remK;
        }
        if (acc) {
            atomicAnd(&alive[v1 >> 5], ~(1u << (v1 & 31)));
            map[(size_t)b * Nv + v1] = v0;
            int rr = __popcll(accM & ((1ull << lane) - 1ull));
            int slot = nk + rr;
            accList[((size_t)b * TGTK + slot) * 2] = v0;
            accList[((size_t)b * TGTK + slot) * 2 + 1] = v1;
        }
        if (spec) mlane[v1] = 64u; // reset registry
        nk += cnt;
        __syncthreads();
        if (nk >= TGTK) break;
        pc = pn;
    }
    for (int i = lane; i < NW; i += 64) aliveW[b * NW + i] = alive[i];
    if (lane == 0) accCnt[b] = (u32)nk;
}

// ---------------- alive ranks: pos[v], alive list, pm[v] = pos[m[v]] ----------------
__global__ __launch_bounds__(256) void k_scan(const u32* aliveW, const int* map,
                                              int* pos, int* pm, int* alist) {
    int b = blockIdx.x, tid = threadIdx.x;
    __shared__ u32 cnt[256];
    __shared__ u32 off[256];
    u32 w = aliveW[b * NW + tid];
    cnt[tid] = __popc(w);
    __syncthreads();
    if (tid == 0) { u32 s = 0; for (int i = 0; i < 256; ++i) { off[i] = s; s += cnt[i]; } }
    __syncthreads();
    u32 base = off[tid];
    int* posb = pos + (size_t)b * Nv;
    int* alb = alist + (size_t)b * Kv;
    for (int bit = 0; bit < 32; ++bit) {
        int v = tid * 32 + bit;
        int p = -1;
        if ((w >> bit) & 1u) {
            if (base < Kv) { p = (int)base; alb[base] = v; }
            base++;
        }
        posb[v] = p;
    }
    __syncthreads();
    const int* mapb = map + (size_t)b * Nv;
    int* pmb = pm + (size_t)b * Nv;
    for (int v = tid; v < Nv; v += 256) pmb[v] = posb[mapb[v]];
}

// ---------------- features: copy surviving rows, then scatter-add absorbed rows ----------------
__global__ void k_fcopy(const float* image, const int* alist, float* outF) {
    int idx = blockIdx.x * 256 + threadIdx.x; // Bn*Kv*16
    if (idx >= Bn * Kv * 16) return;
    int b = idx >> 16, r = idx & 65535;
    int x = r >> 4, f4 = r & 15;
    int src = alist[b * Kv + x];
    const float4* s = (const float4*)(image + ((size_t)(b * Nv + src)) * Fd) + f4;
    float4* d = (float4*)(outF + ((size_t)(b * Kv + x)) * Fd) + f4;
    *d = *s;
}

__global__ __launch_bounds__(64) void k_fscat(const float* image, const int* accList,
                                              const u32* accCnt, const int* pos, float* outF) {
    int b = blockIdx.x >> 12, e = blockIdx.x & 4095;
    if (e >= (int)accCnt[b]) return;
    int v0 = accList[((size_t)b * TGTK + e) * 2];
    int v1 = accList[((size_t)b * TGTK + e) * 2 + 1];
    int x = pos[(size_t)b * Nv + v0];
    if (x < 0) return;
    int f = threadIdx.x;
    atomicAdd(outF + ((size_t)(b * Kv + x)) * Fd + f,
              image[((size_t)(b * Nv + v1)) * Fd + f]);
}

// ---------------- adjacency: merge rows/cols into K-bit bitsets ----------------
__global__ __launch_bounds__(256) void k_merge(const u8* adj, const u32* flags,
                                               const int* pm, u32* outbits) {
    int bi = blockIdx.x; // Bn*Nv
    int b = bi >> 13, i = bi & (Nv - 1);
    int t = pm[(size_t)b * Nv + i];
    if (t < 0) return;
    __shared__ u32 bits[Kv / 32]; // 128 words
    int tid = threadIdx.x;
    if (tid < 128) bits[tid] = 0;
    __syncthreads();
    const int* pmb = pm + (size_t)b * Nv;
    u32 fw = flags[0];
    bool bytefmt = (fw & 1) && (fw & 8);
    auto put = [&](int col) {
        int c = pmb[col];
        if (c >= 0) atomicOr(&bits[c >> 5], 1u << (c & 31));
    };
    if (bytefmt) {
        const uint4* row = (const uint4*)(adj + ((size_t)b * Nv + i) * Nv);
#pragma unroll
        for (int it = 0; it < 2; ++it) {
            uint4 v = row[it * 256 + tid];
            if (v.x | v.y | v.z | v.w) {
                int cb = (it * 256 + tid) * 16;
                u32 wv[4] = { v.x, v.y, v.z, v.w };
                for (int q = 0; q < 4; ++q) {
                    u32 u = wv[q];
                    if (!u) continue;
#pragma unroll
                    for (int kk = 0; kk < 4; ++kk)
                        if ((u >> (8 * kk)) & 0xFFu) put(cb + q * 4 + kk);
                }
            }
        }
    } else {
        const uint4* row = (const uint4*)((const u32*)adj + ((size_t)b * Nv + i) * Nv);
        for (int it = 0; it < 8; ++it) {
            uint4 v = row[it * 256 + tid];
            int cb = (it * 256 + tid) * 4;
            if (v.x) put(cb);
            if (v.y) put(cb + 1);
            if (v.z) put(cb + 2);
            if (v.w) put(cb + 3);
        }
    }
    __syncthreads();
    if (tid < 128) {
        u32 bw = bits[tid];
        if (bw) atomicOr(&outbits[((size_t)b * Kv + t) * 128 + tid], bw);
    }
}

// ---------------- expand bitsets to float adjacency, zero diagonal ----------------
__global__ void k_expand(const u32* outbits, float* out) {
    int idx = blockIdx.x; // Bn*Kv*4
    int tid = threadIdx.x;
    int b = idx >> 14, r = idx & 16383;
    int x = r >> 2, seg = r & 3;
    int c0 = seg * 1024 + tid * 4;
    u32 w = outbits[((size_t)b * Kv + x) * 128 + (c0 >> 5)];
    u32 nib = (w >> (c0 & 31)) & 0xFu;
    float4 f;
    f.x = (nib & 1) ? 1.f : 0.f;
    f.y = (nib & 2) ? 1.f : 0.f;
    f.z = (nib & 4) ? 1.f : 0.f;
    f.w = (nib & 8) ? 1.f : 0.f;
    if (x >= c0 && x < c0 + 4) ((float*)&f)[x - c0] = 0.f;
    *((float4*)(out + ((size_t)(b * Kv + x)) * Kv + c0)) = f;
}

extern "C" void kernel_launch(void* const* d_in, const int* in_sizes, int n_in,
                              void* d_out, int out_size, void* d_ws, size_t ws_size,
                              hipStream_t stream) {
    const u8* adj = (const u8*)d_in[0];
    const float* image = (const float*)d_in[1];
    const float* vs = (const float*)d_in[2];
    const int* edges = (const int*)d_in[3];
    char* ws = (char*)d_ws;
    u32* flags = (u32*)(ws + WS_FLAGS);
    u32* accCnt = (u32*)(ws + WS_ACCCNT);
    u32* fb = (u32*)(ws + WS_FB);
    u32* mm = (u32*)(ws + WS_MM);
    u32* hist = (u32*)(ws + WS_HIST);
    u32* ctr = (u32*)(ws + WS_CTR);
    u32* outbits = (u32*)(ws + WS_OUTBITS);
    u32* off = (u32*)(ws + WS_OFF);
    u64* kfull = (u64*)(ws + WS_KFULL);
    u32* pack = (u32*)(ws + WS_PACK);
    u64* bkey = (u64*)(ws + WS_BKEY);
    u32* bpk = (u32*)(ws + WS_BPK);
    u32* spack = (u32*)(ws + WS_SPACK);
    float* sq = (float*)(ws + WS_SQ);
    u8* bnd = (u8*)(ws + WS_BND);
    int* map = (int*)(ws + WS_MAP);
    int* pos = (int*)(ws + WS_POS);
    int* pm = (int*)(ws + WS_PM);
    u32* aliveW = (u32*)(ws + WS_ALIVEW);
    int* alist = (int*)(ws + WS_ALIST);
    int* accList = (int*)(ws + WS_ACC);
    float* outA = (float*)d_out;
    float* outF = outA + (size_t)Bn * Kv * Kv;

    hipMemsetAsync(d_ws, 0, WS_ZERO_BYTES, stream);
    k_vertex<<<Bn * Nv / 256, 256, 0, stream>>>(adj, flags, image, vs, sq, bnd, map);
    k_edge<<<Bn * Ed / 256, 256, 0, stream>>>(edges, sq, bnd, kfull, pack, mm);
    // value-bucketed sort: 4096 linear bins + per-bin wave bitonic (total order unique)
    k_qhist<<<Bn * Ed / 2048, 256, 0, stream>>>(kfull, mm, hist);
    k_qscan<<<Bn, 1024, 0, stream>>>(hist, off);
    k_qscat<<<Bn * Ed / 256, 256, 0, stream>>>(kfull, pack, mm, off, ctr, bkey, bpk);
    k_qsort<<<Bn * 1024, 256, 0, stream>>>(bkey, bpk, off, spack, fb);
    k_sortFB<<<Bn, 1024, 0, stream>>>(kfull, pack, spack, fb); // early-exit unless fb
    k_greedy<<<Bn, 64, 0, stream>>>(spack, map, aliveW, accList, accCnt);
    k_scan<<<Bn, 256, 0, stream>>>(aliveW, map, pos, pm, alist);
    k_fcopy<<<Bn * Kv * 16 / 256, 256, 0, stream>>>(image, alist, outF);
    k_fscat<<<Bn * TGTK, 64, 0, stream>>>(image, accList, accCnt, pos, outF);
    k_merge<<<Bn * Nv, 256, 0, stream>>>(adj, flags, pm, outbits);
    k_expand<<<Bn * Kv * 4, 256, 0, stream>>>(outbits, outA);
}

// Round 6
// 2023.838 us; speedup vs baseline: 1.8888x; 1.0198x over previous
//
#include <hip/hip_runtime.h>
#include <stdint.h>

typedef unsigned long long u64;
typedef unsigned int u32;
typedef unsigned char u8;

#define Bn 4
#define Nv 8192
#define Fd 64
#define Ed 65536
#define Kv 4096
#define TGTK 4096   // N - K kills allowed
#define NW 256      // alive bitmap words per batch (8192 bits)
#define QB 4096     // value-quantized bins per batch
#define BCAP 256    // per-bin capacity (measured real-data peak ~50; fb guards overflow)

// ---------------- workspace layout (bytes) ----------------
#define WS_FLAGS   ((size_t)0)                          // u32 adj-format presence bits
#define WS_ACCCNT  ((size_t)256)                        // Bn u32
#define WS_FB      ((size_t)512)                        // u32 fallback flag
#define WS_MM      ((size_t)768)                        // Bn*2 u32: max(~minbits), max(bits)
#define WS_HIST    ((size_t)4096)                       // Bn*QB u32 = 64 KB
#define WS_CTR     (WS_HIST + (size_t)Bn*QB*4)          // Bn*QB u32 = 64 KB
#define WS_ZERO_BYTES (WS_CTR + (size_t)Bn*QB*4)        // memset range: control+hist+ctr only
#define WS_OUTBITS (WS_ZERO_BYTES)                      // Bn*Kv*128 u32 = 8 MB (zeroed in k_qscat)
#define WS_OFF     (WS_OUTBITS + (size_t)Bn*Kv*128*4)   // Bn*4104 u32 (4097 used)
#define WS_KFULL   (WS_OFF + (size_t)Bn*4104*4)         // Bn*Ed u64 (cost<<16|e)
#define WS_PACK    (WS_KFULL + (size_t)Bn*Ed*8)         // Bn*Ed u32
#define WS_BKEY    (WS_PACK + (size_t)Bn*Ed*4)          // Bn*Ed u64 binned keys
#define WS_BPK     (WS_BKEY + (size_t)Bn*Ed*8)          // Bn*Ed u32 binned packs
#define WS_SPACK   (WS_BPK + (size_t)Bn*Ed*4)           // Bn*Ed u32 sorted packs
#define WS_SQ      (WS_SPACK + (size_t)Bn*Ed*4)         // Bn*Nv f32
#define WS_BND     (WS_SQ + (size_t)Bn*Nv*4)            // Bn*Nv u8
#define WS_MAP     (WS_BND + (size_t)Bn*Nv)             // Bn*Nv i32
#define WS_POS     (WS_MAP + (size_t)Bn*Nv*4)           // Bn*Nv i32
#define WS_PM      (WS_POS + (size_t)Bn*Nv*4)           // Bn*Nv i32
#define WS_ALIVEW  (WS_PM + (size_t)Bn*Nv*4)            // Bn*NW u32
#define WS_ALIST   (WS_ALIVEW + (size_t)Bn*NW*4)        // Bn*Kv i32
#define WS_ACC     (WS_ALIST + (size_t)Bn*Kv*4)         // Bn*TGTK*2 i32

// ---------------- per-vertex: numpy-pairwise sqnorm, boundary, map init + adj format detect ----------------
__global__ void k_vertex(const u8* adj, u32* flags, const float* image, const float* vs,
                         float* sq, u8* bnd, int* map) {
#pragma clang fp contract(off)
    int idx = blockIdx.x * 256 + threadIdx.x; // b*Nv + v, exactly 32768 threads
    const float* row = image + (size_t)idx * Fd;
    float r[8];
#pragma unroll
    for (int j = 0; j < 8; ++j) r[j] = row[j] * row[j];
#pragma unroll
    for (int i = 8; i < 64; i += 8)
#pragma unroll
        for (int j = 0; j < 8; ++j) r[j] += row[i + j] * row[i + j];
    float s = ((r[0] + r[1]) + (r[2] + r[3])) + ((r[4] + r[5]) + (r[6] + r[7]));
    sq[idx] = s;
    float x = vs[(size_t)idx * 2], y = vs[(size_t)idx * 2 + 1];
    const float LO = 0.05f;
    const float HI = (float)(1.0 - 0.05);
    bnd[idx] = ((x < LO) || (x > HI) || (y < LO) || (y > HI)) ? 1 : 0;
    map[idx] = idx & (Nv - 1);
    // adj format detection: sample first 2 MB for nonzero bytes at each offset%4
    const u32* w = (const u32*)adj;
    bool f0 = false, f1 = false, f2 = false, f3 = false;
    for (int i = idx; i < (1 << 19); i += 32768) {
        u32 v = w[i];
        f0 |= (v & 0x000000FFu) != 0;
        f1 |= (v & 0x0000FF00u) != 0;
        f2 |= (v & 0x00FF0000u) != 0;
        f3 |= (v & 0xFF000000u) != 0;
    }
    u32 m = 0;
    if (__ballot(f0)) m |= 1;
    if (__ballot(f1)) m |= 2;
    if (__ballot(f2)) m |= 4;
    if (__ballot(f3)) m |= 8;
    if ((threadIdx.x & 63) == 0 && m) atomicOr(flags, m);
}

// ---------------- per-edge: full key (cost<<16|e), pack, per-batch cost min/max ----------------
__global__ void k_edge(const int* edges, const float* sq, const u8* bnd,
                       u64* kfull, u32* pack, u32* mm) {
    int idx = blockIdx.x * 256 + threadIdx.x; // b*Ed + e (blocks never straddle batches)
    if (idx >= Bn * Ed) return;
    int b = idx >> 16, e = idx & (Ed - 1);
    int v0 = edges[(size_t)b * 2 * Ed + e];
    int v1 = edges[(size_t)b * 2 * Ed + Ed + e];
    float c = sq[b * Nv + v0] + sq[b * Nv + v1];
    u32 cb = __float_as_uint(c); // cost >= 0 -> unsigned bit order == float order
    kfull[idx] = ((u64)cb << 16) | (u32)e;
    u32 okk = (!bnd[b * Nv + v0] && !bnd[b * Nv + v1]) ? 1u : 0u;
    pack[idx] = (u32)v0 | ((u32)v1 << 13) | (okk << 26);
    // wave-reduce min/max of cost bits, one atomic pair per wave
    u32 mn = cb, mx = cb;
#pragma unroll
    for (int o = 32; o; o >>= 1) {
        u32 a = (u32)__shfl_xor((int)mn, o);
        u32 d = (u32)__shfl_xor((int)mx, o);
        mn = mn < a ? mn : a;
        mx = mx > d ? mx : d;
    }
    if ((threadIdx.x & 63) == 0) {
        atomicMax(&mm[b * 2], ~mn);     // min via max of complement (zero-init safe)
        atomicMax(&mm[b * 2 + 1], mx);
    }
}

__device__ __forceinline__ int qbin(u32 cb, u32 mm0, u32 mm1) {
    float minC = __uint_as_float(~mm0);
    float maxC = __uint_as_float(mm1);
    float span = maxC - minC;
    float scale = (float)QB / (span > 1e-30f ? span : 1e-30f);
    int bin = (int)((__uint_as_float(cb) - minC) * scale);
    return bin < 0 ? 0 : (bin > QB - 1 ? QB - 1 : bin);
}

// ---------------- bucket histogram (LDS per block -> global) ----------------
__global__ __launch_bounds__(256) void k_qhist(const u64* kfull, const u32* mm, u32* hist) {
    __shared__ u32 lh[QB];
    int tid = threadIdx.x;
    for (int i = tid; i < QB; i += 256) lh[i] = 0;
    __syncthreads();
    size_t base = (size_t)blockIdx.x * 2048; // 128 blocks/batch, batch-aligned
    int b = (int)(base >> 16);
    u32 mm0 = mm[b * 2], mm1 = mm[b * 2 + 1];
#pragma unroll
    for (int r = 0; r < 8; ++r) {
        u32 cb = (u32)(kfull[base + r * 256 + tid] >> 16);
        atomicAdd(&lh[qbin(cb, mm0, mm1)], 1u);
    }
    __syncthreads();
    for (int i = tid; i < QB; i += 256) {
        u32 v = lh[i];
        if (v) atomicAdd(&hist[b * QB + i], v);
    }
}

// ---------------- scan 4096 bins per batch -> off[4097] ----------------
__global__ __launch_bounds__(1024) void k_qscan(const u32* hist, u32* off) {
    int b = blockIdx.x, tid = threadIdx.x;
    const u32* h = hist + b * QB;
    u32 h4[4];
    u32 s = 0;
#pragma unroll
    for (int q = 0; q < 4; ++q) { h4[q] = h[tid * 4 + q]; s += h4[q]; }
    __shared__ u32 sc[1024];
    sc[tid] = s;
    __syncthreads();
    for (int o = 1; o < 1024; o <<= 1) {
        u32 t = (tid >= o) ? sc[tid - o] : 0u;
        __syncthreads();
        sc[tid] += t;
        __syncthreads();
    }
    u32 run = sc[tid] - s; // exclusive
    u32* ob = off + b * 4104;
#pragma unroll
    for (int q = 0; q < 4; ++q) { ob[tid * 4 + q] = run; run += h4[q]; }
    if (tid == 1023) ob[QB] = sc[1023];
}

// ---------------- scatter into bin segments (unstable; total order restored by binsort) ----------------
// also zeroes outbits (8 MB) for k_merge, replacing most of the big memset
__global__ void k_qscat(const u64* kfull, const u32* pack, const u32* mm, const u32* off,
                        u32* ctr, u64* bkey, u32* bpk, uint4* outbits4) {
    int idx = blockIdx.x * 256 + threadIdx.x;
    if (idx >= Bn * Ed) return;
    uint4 z = make_uint4(0, 0, 0, 0);
#pragma unroll
    for (int q = 0; q < 2; ++q) outbits4[(size_t)q * Bn * Ed + idx] = z; // 2M u32 total
    int b = idx >> 16;
    u64 kf = kfull[idx];
    u32 cb = (u32)(kf >> 16);
    u32 e = (u32)(kf & 0xFFFFu);
    int bin = qbin(cb, mm[b * 2], mm[b * 2 + 1]);
    u32 slot = atomicAdd(&ctr[b * QB + bin], 1u);
    u32 dst = off[b * 4104 + bin] + slot; // always within segment (segment len == bin count)
    bkey[(size_t)b * Ed + dst] = ((u64)cb << 24) | ((u64)e << 8) | (u64)(slot & 255u);
    bpk[(size_t)b * Ed + dst] = pack[idx];
}

// ---------------- per-bin sort: one wave per bin, barrier-free (intra-wave DS ordering) ----------------
__global__ __launch_bounds__(256) void k_qsort(const u64* bkey, const u32* bpk, const u32* off,
                                               u32* spack, u32* fb) {
    __shared__ u64 sk[4][BCAP];
    int wave = threadIdx.x >> 6, lane = threadIdx.x & 63;
    int b = blockIdx.x >> 10;
    int bin = (blockIdx.x & 1023) * 4 + wave;
    u32 start = off[b * 4104 + bin];
    u32 end = off[b * 4104 + bin + 1];
    int len = (int)(end - start);
    if (len <= 0) return;                              // per-wave exit: no barriers in kernel
    if (len > BCAP) { if (lane == 0) atomicOr(fb, 1u); return; }
    int m = 2;
    while (m < len) m <<= 1;                           // adaptive network size (wave-uniform)
    const u64* kb = bkey + (size_t)b * Ed + start;
    u64* s = sk[wave];
    for (int i = lane; i < m; i += 64) s[i] = (i < len) ? kb[i] : ~0ull;
    __builtin_amdgcn_wave_barrier();
    // single wave owns this LDS slice: DS pipe processes a wave's LDS ops in
    // program order, so no s_barrier / waitcnt drain is needed between passes.
    for (int k = 2; k <= m; k <<= 1) {
        for (int j = k >> 1; j > 0; j >>= 1) {
            for (int t = lane; t < (m >> 1); t += 64) {
                int i = ((t & ~(j - 1)) << 1) | (t & (j - 1));
                bool asc = ((i & k) == 0);
                u64 a = s[i], c = s[i | j];
                if ((a > c) == asc) { s[i] = c; s[i | j] = a; }
            }
            __builtin_amdgcn_wave_barrier();
        }
    }
    const u32* pb = bpk + (size_t)b * Ed + start;
    u32* so = spack + (size_t)b * Ed + start;
    for (int r = lane; r < len; r += 64) {
        u32 sl = (u32)(s[r] & 255u);
        so[r] = pb[sl];
    }
}

// ---------------- fallback: full in-block bitonic sort + gather (early-exit unless fb) ----------------
__global__ __launch_bounds__(1024) void k_sortFB(u64* kfull, const u32* pack, u32* spack,
                                                 const u32* fb) {
    if (*fb == 0) return;
    int b = blockIdx.x;
    u64* kb = kfull + (size_t)b * Ed;
    __shared__ u64 s[8192];
    int tid = threadIdx.x;
    for (int ch = 0; ch < 8; ++ch) { // local sort of 8 chunks
        u64* cb = kb + ch * 8192;
        int gb = ch * 8192;
        for (int p = 0; p < 8; ++p) s[p * 1024 + tid] = cb[p * 1024 + tid];
        __syncthreads();
        for (int k = 2; k <= 8192; k <<= 1)
            for (int j = k >> 1; j > 0; j >>= 1) {
                for (int p = 0; p < 4; ++p) {
                    int t = p * 1024 + tid;
                    int i = ((t & ~(j - 1)) << 1) | (t & (j - 1));
                    bool asc = (((gb + i) & k) == 0);
                    u64 a = s[i], c = s[i | j];
                    if ((a > c) == asc) { s[i] = c; s[i | j] = a; }
                }
                __syncthreads();
            }
        for (int p = 0; p < 8; ++p) cb[p * 1024 + tid] = s[p * 1024 + tid];
        __syncthreads();
    }
    for (int k = 16384; k <= 65536; k <<= 1) { // merge stages
        for (int j = k >> 1; j >= 8192; j >>= 1) {
            for (int p = 0; p < 32; ++p) {
                int t = p * 1024 + tid;
                int i = ((t & ~(j - 1)) << 1) | (t & (j - 1));
                bool asc = ((i & k) == 0);
                u64 a = kb[i], c = kb[i | j];
                if ((a > c) == asc) { kb[i] = c; kb[i | j] = a; }
            }
            __syncthreads();
        }
        for (int ch = 0; ch < 8; ++ch) {
            u64* cb = kb + ch * 8192;
            bool asc = (((ch * 8192) & k) == 0);
            for (int p = 0; p < 8; ++p) s[p * 1024 + tid] = cb[p * 1024 + tid];
            __syncthreads();
            for (int j = 4096; j > 0; j >>= 1) {
                for (int p = 0; p < 4; ++p) {
                    int t = p * 1024 + tid;
                    int i = ((t & ~(j - 1)) << 1) | (t & (j - 1));
                    u64 a = s[i], c = s[i | j];
                    if ((a > c) == asc) { s[i] = c; s[i | j] = a; }
                }
                __syncthreads();
            }
            for (int p = 0; p < 8; ++p) cb[p * 1024 + tid] = s[p * 1024 + tid];
            __syncthreads();
        }
    }
    for (int i = tid; i < Ed; i += 1024)
        spack[(size_t)b * Ed + i] = pack[(size_t)b * Ed + (u32)(kb[i] & 0xFFFFu)];
}

// ---------------- sequential greedy collapse: 1 wave per batch, barrier-free ----------------
// single-wave block: ballots/shfl are wave-synchronous; LDS ops execute in
// program order on the DS pipe. Removing __syncthreads keeps the global
// prefetch (pn) in flight across the group instead of draining vmcnt(0).
__global__ __launch_bounds__(64) void k_greedy(const u32* spack, int* map, u32* aliveW,
                                               int* accList, u32* accCnt) {
    int b = blockIdx.x;
    int lane = threadIdx.x;
    __shared__ u32 alive[NW];
    __shared__ u32 mlane[Nv]; // per-vertex: min lane registering vertex as its v1 this group
    for (int i = lane; i < NW; i += 64) alive[i] = 0xFFFFFFFFu;
    for (int i = lane; i < Nv; i += 64) mlane[i] = 64u;
    const u32* sp = spack + (size_t)b * Ed;
    u32 pc = sp[lane]; // prefetch group 0
    __builtin_amdgcn_wave_barrier();
    int nk = 0;
    const int G = Ed / 64;
    for (int g = 0; g < G; ++g) {
        u32 pn = (g + 1 < G) ? sp[(g + 1) * 64 + lane] : 0u; // stays in flight (no vmcnt drain)
        int v0 = pc & 8191;
        int v1 = (pc >> 13) & 8191;
        bool okk = (pc >> 26) & 1u;
        bool a0 = (alive[v0 >> 5] >> (v0 & 31)) & 1u;
        bool a1 = (alive[v1 >> 5] >> (v1 & 31)) & 1u;
        bool spec = okk && a0 && a1; // exact unless an earlier in-group accept kills my endpoint
        if (spec) atomicMin(&mlane[v1], (u32)lane);
        __builtin_amdgcn_wave_barrier();
        bool conf = false;
        if (spec) conf = (mlane[v0] < (u32)lane) || (mlane[v1] < (u32)lane);
        u64 specM = __ballot(spec);
        u64 confM = __ballot(conf);
        u64 accM = specM & ~confM; // non-conflicted speculative accepts are exact
        u64 rem = confM;           // resolve conflicted lanes in sequential (edge) order
        while (rem) {
            int l = __ffsll((unsigned long long)rem) - 1;
            rem &= rem - 1;
            int bv0 = __shfl(v0, l);
            int bv1 = __shfl(v1, l);
            bool killer = ((accM >> lane) & 1ull) && (lane < l) && (v1 == bv0 || v1 == bv1);
            if (__ballot(killer) == 0ull) accM |= 1ull << l;
        }
        int cnt = __popcll(accM);
        int remK = TGTK - nk;
        bool acc = (accM >> lane) & 1ull;
        if (cnt > remK) { // kill-count cap: keep first remK accepts
            int rr = __popcll(accM & ((1ull << lane) - 1ull));
            if (acc && rr >= remK) acc = false;
            accM = __ballot(acc);
            cnt = remK;
        }
        if (acc) {
            atomicAnd(&alive[v1 >> 5], ~(1u << (v1 & 31)));
            map[(size_t)b * Nv + v1] = v0;
            int rr = __popcll(accM & ((1ull << lane) - 1ull));
            int slot = nk + rr;
            accList[((size_t)b * TGTK + slot) * 2] = v0;
            accList[((size_t)b * TGTK + slot) * 2 + 1] = v1;
        }
        if (spec) mlane[v1] = 64u; // reset registry (ordered after all reads: program order)
        nk += cnt;
        __builtin_amdgcn_wave_barrier();
        if (nk >= TGTK) break;
        pc = pn;
    }
    for (int i = lane; i < NW; i += 64) aliveW[b * NW + i] = alive[i];
    if (lane == 0) accCnt[b] = (u32)nk;
}

// ---------------- alive ranks: pos[v], alive list, pm[v] = pos[m[v]] ----------------
__global__ __launch_bounds__(256) void k_scan(const u32* aliveW, const int* map,
                                              int* pos, int* pm, int* alist) {
    int b = blockIdx.x, tid = threadIdx.x;
    __shared__ u32 cnt[256];
    __shared__ u32 off[256];
    u32 w = aliveW[b * NW + tid];
    cnt[tid] = __popc(w);
    __syncthreads();
    if (tid == 0) { u32 s = 0; for (int i = 0; i < 256; ++i) { off[i] = s; s += cnt[i]; } }
    __syncthreads();
    u32 base = off[tid];
    int* posb = pos + (size_t)b * Nv;
    int* alb = alist + (size_t)b * Kv;
    for (int bit = 0; bit < 32; ++bit) {
        int v = tid * 32 + bit;
        int p = -1;
        if ((w >> bit) & 1u) {
            if (base < Kv) { p = (int)base; alb[base] = v; }
            base++;
        }
        posb[v] = p;
    }
    __syncthreads();
    const int* mapb = map + (size_t)b * Nv;
    int* pmb = pm + (size_t)b * Nv;
    for (int v = tid; v < Nv; v += 256) pmb[v] = posb[mapb[v]];
}

// ---------------- features: copy surviving rows, then scatter-add absorbed rows ----------------
__global__ void k_fcopy(const float* image, const int* alist, float* outF) {
    int idx = blockIdx.x * 256 + threadIdx.x; // Bn*Kv*16
    if (idx >= Bn * Kv * 16) return;
    int b = idx >> 16, r = idx & 65535;
    int x = r >> 4, f4 = r & 15;
    int src = alist[b * Kv + x];
    const float4* s = (const float4*)(image + ((size_t)(b * Nv + src)) * Fd) + f4;
    float4* d = (float4*)(outF + ((size_t)(b * Kv + x)) * Fd) + f4;
    *d = *s;
}

__global__ __launch_bounds__(64) void k_fscat(const float* image, const int* accList,
                                              const u32* accCnt, const int* pos, float* outF) {
    int b = blockIdx.x >> 12, e = blockIdx.x & 4095;
    if (e >= (int)accCnt[b]) return;
    int v0 = accList[((size_t)b * TGTK + e) * 2];
    int v1 = accList[((size_t)b * TGTK + e) * 2 + 1];
    int x = pos[(size_t)b * Nv + v0];
    if (x < 0) return;
    int f = threadIdx.x;
    atomicAdd(outF + ((size_t)(b * Kv + x)) * Fd + f,
              image[((size_t)(b * Nv + v1)) * Fd + f]);
}

// ---------------- adjacency: merge rows/cols into K-bit bitsets ----------------
__global__ __launch_bounds__(256) void k_merge(const u8* adj, const u32* flags,
                                               const int* pm, u32* outbits) {
    int bi = blockIdx.x; // Bn*Nv
    int b = bi >> 13, i = bi & (Nv - 1);
    int t = pm[(size_t)b * Nv + i];
    if (t < 0) return;
    __shared__ u32 bits[Kv / 32]; // 128 words
    int tid = threadIdx.x;
    if (tid < 128) bits[tid] = 0;
    __syncthreads();
    const int* pmb = pm + (size_t)b * Nv;
    u32 fw = flags[0];
    bool bytefmt = (fw & 1) && (fw & 8);
    auto put = [&](int col) {
        int c = pmb[col];
        if (c >= 0) atomicOr(&bits[c >> 5], 1u << (c & 31));
    };
    if (bytefmt) {
        const uint4* row = (const uint4*)(adj + ((size_t)b * Nv + i) * Nv);
#pragma unroll
        for (int it = 0; it < 2; ++it) {
            uint4 v = row[it * 256 + tid];
            if (v.x | v.y | v.z | v.w) {
                int cb = (it * 256 + tid) * 16;
                u32 wv[4] = { v.x, v.y, v.z, v.w };
                for (int q = 0; q < 4; ++q) {
                    u32 u = wv[q];
                    if (!u) continue;
#pragma unroll
                    for (int kk = 0; kk < 4; ++kk)
                        if ((u >> (8 * kk)) & 0xFFu) put(cb + q * 4 + kk);
                }
            }
        }
    } else {
        const uint4* row = (const uint4*)((const u32*)adj + ((size_t)b * Nv + i) * Nv);
        for (int it = 0; it < 8; ++it) {
            uint4 v = row[it * 256 + tid];
            int cb = (it * 256 + tid) * 4;
            if (v.x) put(cb);
            if (v.y) put(cb + 1);
            if (v.z) put(cb + 2);
            if (v.w) put(cb + 3);
        }
    }
    __syncthreads();
    if (tid < 128) {
        u32 bw = bits[tid];
        if (bw) atomicOr(&outbits[((size_t)b * Kv + t) * 128 + tid], bw);
    }
}

// ---------------- expand bitsets to float adjacency, zero diagonal ----------------
__global__ void k_expand(const u32* outbits, float* out) {
    int idx = blockIdx.x; // Bn*Kv*4
    int tid = threadIdx.x;
    int b = idx >> 14, r = idx & 16383;
    int x = r >> 2, seg = r & 3;
    int c0 = seg * 1024 + tid * 4;
    u32 w = outbits[((size_t)b * Kv + x) * 128 + (c0 >> 5)];
    u32 nib = (w >> (c0 & 31)) & 0xFu;
    float4 f;
    f.x = (nib & 1) ? 1.f : 0.f;
    f.y = (nib & 2) ? 1.f : 0.f;
    f.z = (nib & 4) ? 1.f : 0.f;
    f.w = (nib & 8) ? 1.f : 0.f;
    if (x >= c0 && x < c0 + 4) ((float*)&f)[x - c0] = 0.f;
    *((float4*)(out + ((size_t)(b * Kv + x)) * Kv + c0)) = f;
}

extern "C" void kernel_launch(void* const* d_in, const int* in_sizes, int n_in,
                              void* d_out, int out_size, void* d_ws, size_t ws_size,
                              hipStream_t stream) {
    const u8* adj = (const u8*)d_in[0];
    const float* image = (const float*)d_in[1];
    const float* vs = (const float*)d_in[2];
    const int* edges = (const int*)d_in[3];
    char* ws = (char*)d_ws;
    u32* flags = (u32*)(ws + WS_FLAGS);
    u32* accCnt = (u32*)(ws + WS_ACCCNT);
    u32* fb = (u32*)(ws + WS_FB);
    u32* mm = (u32*)(ws + WS_MM);
    u32* hist = (u32*)(ws + WS_HIST);
    u32* ctr = (u32*)(ws + WS_CTR);
    u32* outbits = (u32*)(ws + WS_OUTBITS);
    u32* off = (u32*)(ws + WS_OFF);
    u64* kfull = (u64*)(ws + WS_KFULL);
    u32* pack = (u32*)(ws + WS_PACK);
    u64* bkey = (u64*)(ws + WS_BKEY);
    u32* bpk = (u32*)(ws + WS_BPK);
    u32* spack = (u32*)(ws + WS_SPACK);
    float* sq = (float*)(ws + WS_SQ);
    u8* bnd = (u8*)(ws + WS_BND);
    int* map = (int*)(ws + WS_MAP);
    int* pos = (int*)(ws + WS_POS);
    int* pm = (int*)(ws + WS_PM);
    u32* aliveW = (u32*)(ws + WS_ALIVEW);
    int* alist = (int*)(ws + WS_ALIST);
    int* accList = (int*)(ws + WS_ACC);
    float* outA = (float*)d_out;
    float* outF = outA + (size_t)Bn * Kv * Kv;

    hipMemsetAsync(d_ws, 0, WS_ZERO_BYTES, stream); // 132 KB control region only
    k_vertex<<<Bn * Nv / 256, 256, 0, stream>>>(adj, flags, image, vs, sq, bnd, map);
    k_edge<<<Bn * Ed / 256, 256, 0, stream>>>(edges, sq, bnd, kfull, pack, mm);
    // value-bucketed sort: 4096 linear bins + per-bin wave bitonic (total order unique)
    k_qhist<<<Bn * Ed / 2048, 256, 0, stream>>>(kfull, mm, hist);
    k_qscan<<<Bn, 1024, 0, stream>>>(hist, off);
    k_qscat<<<Bn * Ed / 256, 256, 0, stream>>>(kfull, pack, mm, off, ctr, bkey, bpk,
                                               (uint4*)outbits);
    k_qsort<<<Bn * 1024, 256, 0, stream>>>(bkey, bpk, off, spack, fb);
    k_sortFB<<<Bn, 1024, 0, stream>>>(kfull, pack, spack, fb); // early-exit unless fb
    k_greedy<<<Bn, 64, 0, stream>>>(spack, map, aliveW, accList, accCnt);
    k_scan<<<Bn, 256, 0, stream>>>(aliveW, map, pos, pm, alist);
    k_fcopy<<<Bn * Kv * 16 / 256, 256, 0, stream>>>(image, alist, outF);
    k_fscat<<<Bn * TGTK, 64, 0, stream>>>(image, accList, accCnt, pos, outF);
    k_merge<<<Bn * Nv, 256, 0, stream>>>(adj, flags, pm, outbits);
    k_expand<<<Bn * Kv * 4, 256, 0, stream>>>(outbits, outA);
}